// Round 2
// baseline (4513.803 us; speedup 1.0000x reference)
//
#include <hip/hip_runtime.h>
#include <math.h>

#define NN 20000
#define NE 320000

static_assert(NE % 256 == 0, "edge grid must be exact (barriers in kernel)");

__device__ __forceinline__ float frelu(float x){ return fmaxf(x, 0.0f); }

// Recompute geometry + edge embedding. Fills eemb[16] and sh1[3].
// Small weights (em_*) stay in global: uniform s_loads, K$-resident.
__device__ __forceinline__ void edge_embed(
    int e, int s, int d,
    const float* __restrict__ pos,
    const float* __restrict__ edge_bond,
    const float* __restrict__ em_w1, const float* __restrict__ em_b1,
    const float* __restrict__ em_w2, const float* __restrict__ em_b2,
    float* eemb, float* sh1)
{
    float vx = pos[d*3+0] - pos[s*3+0];
    float vy = pos[d*3+1] - pos[s*3+1];
    float vz = pos[d*3+2] - pos[s*3+2];
    float d2 = vx*vx + vy*vy + vz*vz + 1e-12f;
    float dist = sqrtf(d2);
    float inv = 1.0f / (dist + 1e-8f);
    const float SQ3 = 1.7320508075688772f;
    sh1[0] = SQ3 * vx * inv;
    sh1[1] = SQ3 * vy * inv;
    sh1[2] = SQ3 * vz * inv;

    float ein[42];
    #pragma unroll
    for (int t = 0; t < 10; ++t) ein[t] = edge_bond[e*10 + t];
    const float coeff = -19.22f;            // -0.5 / (5/31)^2
    const float step  = 5.0f / 31.0f;
    #pragma unroll
    for (int k = 0; k < 32; ++k) {
        float dd = dist - step * (float)k;
        ein[10+k] = __expf(coeff * dd * dd);
    }

    float t1[16];
    #pragma unroll
    for (int j = 0; j < 16; ++j) t1[j] = em_b1[j];
    #pragma unroll
    for (int t = 0; t < 42; ++t) {
        float v = ein[t];
        #pragma unroll
        for (int j = 0; j < 16; ++j) t1[j] += v * em_w1[t*16 + j];
    }
    #pragma unroll
    for (int j = 0; j < 16; ++j) t1[j] = frelu(t1[j]);

    #pragma unroll
    for (int j = 0; j < 16; ++j) eemb[j] = em_b2[j];
    #pragma unroll
    for (int t = 0; t < 16; ++t) {
        float v = t1[t];
        #pragma unroll
        for (int j = 0; j < 16; ++j) eemb[j] += v * em_w2[t*16 + j];
    }
}

// Cooperative load of a 48 x C column-chunk of w2 (row stride NC) into LDS.
// 48*C is a multiple of 1024 for all call sites -> no tail, all threads loop equally.
template<int C, int NC>
__device__ __forceinline__ void load_chunk(float* sW2, const float* __restrict__ w2, int baseCol) {
    for (int i = threadIdx.x * 4; i < 48 * C; i += 1024) {
        int j = i / C;
        int c = i - j * C;
        *reinterpret_cast<float4*>(&sW2[i]) =
            *reinterpret_cast<const float4*>(&w2[j * NC + baseCol + c]);
    }
}

// out0[k] += sum_{ul<8} s[ubase+ul] * (b2[(ubase+ul)*16+k] + sum_j h[j]*sW2[j*128+ul*16+k])
// LDS reads are lane-uniform -> broadcast, conflict-free.
__device__ __forceinline__ void compute_wa8(const float* sW2, const float h[48],
                                            const float* __restrict__ b2,
                                            const float* __restrict__ srow,
                                            int ubase, float out0[16])
{
    for (int ul = 0; ul < 8; ++ul) {
        int u = ubase + ul;
        float wk[16];
        #pragma unroll
        for (int k = 0; k < 16; ++k) wk[k] = b2[u*16 + k];
        #pragma unroll
        for (int j = 0; j < 48; ++j) {
            float hv = h[j];
            const float4* wr = reinterpret_cast<const float4*>(&sW2[j*128 + ul*16]);
            float4 w0 = wr[0], w1 = wr[1], w2v = wr[2], w3 = wr[3];
            wk[ 0] += hv*w0.x; wk[ 1] += hv*w0.y; wk[ 2] += hv*w0.z; wk[ 3] += hv*w0.w;
            wk[ 4] += hv*w1.x; wk[ 5] += hv*w1.y; wk[ 6] += hv*w1.z; wk[ 7] += hv*w1.w;
            wk[ 8] += hv*w2v.x; wk[ 9] += hv*w2v.y; wk[10] += hv*w2v.z; wk[11] += hv*w2v.w;
            wk[12] += hv*w3.x; wk[13] += hv*w3.y; wk[14] += hv*w3.z; wk[15] += hv*w3.w;
        }
        float su = srow[u];
        #pragma unroll
        for (int k = 0; k < 16; ++k) out0[k] += su * wk[k];
    }
}

__global__ __launch_bounds__(256)
void k_node_feat(const int* __restrict__ x_cat, const float* __restrict__ x_scalar,
                 const float* __restrict__ emb, const float* __restrict__ node_w,
                 const float* __restrict__ node_b, float* __restrict__ node0)
{
    int n = blockIdx.x * 256 + threadIdx.x;
    if (n >= NN) return;
    float acc[16];
    #pragma unroll
    for (int k = 0; k < 16; ++k) acc[k] = node_b[k];
    #pragma unroll
    for (int c = 0; c < 10; ++c) {
        int idx = x_cat[n*10 + c];
        const float4* row = reinterpret_cast<const float4*>(emb + (c*119 + idx)*16);
        #pragma unroll
        for (int k = 0; k < 4; ++k) {
            float4 q = row[k];
            acc[4*k+0] += q.x; acc[4*k+1] += q.y; acc[4*k+2] += q.z; acc[4*k+3] += q.w;
        }
    }
    #pragma unroll
    for (int t = 0; t < 32; ++t) {
        float xs = x_scalar[n*32 + t];
        #pragma unroll
        for (int k = 0; k < 16; ++k) acc[k] += xs * node_w[t*16 + k];
    }
    #pragma unroll
    for (int k = 0; k < 16; ++k) node0[n*16 + k] = acc[k];
}

__global__ __launch_bounds__(256)
void k_edge_l1(const int* __restrict__ ei, const float* __restrict__ pos,
               const float* __restrict__ edge_bond,
               const float* __restrict__ em_w1, const float* __restrict__ em_b1,
               const float* __restrict__ em_w2, const float* __restrict__ em_b2,
               const float* __restrict__ w1, const float* __restrict__ b1,
               const float* __restrict__ w2, const float* __restrict__ b2,
               const float* __restrict__ node0,
               float* __restrict__ accum, float* __restrict__ cnt)
{
    __shared__ float sW2[48*128];   // 24 KB
    int e = blockIdx.x * 256 + threadIdx.x;
    int s = ei[e], d = ei[NE + e];

    load_chunk<128,320>(sW2, w2, 0);   // chunk0 in flight under h-compute

    float ea[48];
    float sh1[3];
    edge_embed(e, s, d, pos, edge_bond, em_w1, em_b1, em_w2, em_b2, ea, sh1);
    {
        const float4* rs = reinterpret_cast<const float4*>(node0 + s*16);
        const float4* rd = reinterpret_cast<const float4*>(node0 + d*16);
        #pragma unroll
        for (int k = 0; k < 4; ++k) {
            float4 q = rs[k];
            ea[16+4*k] = q.x; ea[17+4*k] = q.y; ea[18+4*k] = q.z; ea[19+4*k] = q.w;
            float4 r = rd[k];
            ea[32+4*k] = r.x; ea[33+4*k] = r.y; ea[34+4*k] = r.z; ea[35+4*k] = r.w;
        }
    }

    // h = relu(ea @ W1 + b1)   (w1 small: uniform global s_loads, K$-hot)
    float h[48];
    #pragma unroll
    for (int j = 0; j < 48; ++j) h[j] = b1[j];
    #pragma unroll
    for (int t = 0; t < 48; ++t) {
        float v = ea[t];
        #pragma unroll
        for (int j = 0; j < 48; ++j) h[j] += v * w1[t*48 + j];
    }
    #pragma unroll
    for (int j = 0; j < 48; ++j) h[j] = frelu(h[j]);

    float out0[16];
    #pragma unroll
    for (int k = 0; k < 16; ++k) out0[k] = 0.0f;

    __syncthreads();
    compute_wa8(sW2, h, b2, node0 + d*16, 0, out0);
    __syncthreads();
    load_chunk<128,320>(sW2, w2, 128);
    __syncthreads();
    compute_wa8(sW2, h, b2, node0 + d*16, 8, out0);
    __syncthreads();
    load_chunk<64,320>(sW2, w2, 256);
    __syncthreads();

    // wb tail: stride 64
    float ob[4] = {0.f, 0.f, 0.f, 0.f};
    for (int u = 0; u < 16; ++u) {
        float wq[4];
        #pragma unroll
        for (int q = 0; q < 4; ++q) wq[q] = b2[256 + u*4 + q];
        #pragma unroll
        for (int j = 0; j < 48; ++j) {
            float hv = h[j];
            const float4 w = *reinterpret_cast<const float4*>(&sW2[j*64 + u*4]);
            wq[0] += hv*w.x; wq[1] += hv*w.y; wq[2] += hv*w.z; wq[3] += hv*w.w;
        }
        float su = node0[d*16 + u];
        #pragma unroll
        for (int q = 0; q < 4; ++q) ob[q] += su * wq[q];
    }

    const float a = 0.25f;                     // 1/sqrt(16)
    float* out = accum + (size_t)s * 28;
    #pragma unroll
    for (int k = 0; k < 16; ++k) atomicAdd(out + k, out0[k] * a);
    #pragma unroll
    for (int q = 0; q < 4; ++q)
        #pragma unroll
        for (int i = 0; i < 3; ++i)
            atomicAdd(out + 16 + q*3 + i, ob[q] * a * sh1[i]);
    atomicAdd(cnt + s, 1.0f);
}

__global__ __launch_bounds__(256)
void k_edge_l2(const int* __restrict__ ei, const float* __restrict__ pos,
               const float* __restrict__ edge_bond,
               const float* __restrict__ em_w1, const float* __restrict__ em_b1,
               const float* __restrict__ em_w2, const float* __restrict__ em_b2,
               const float* __restrict__ w1, const float* __restrict__ b1,
               const float* __restrict__ w2, const float* __restrict__ b2,
               const float* __restrict__ node1,
               float* __restrict__ accum2)
{
    __shared__ float sW2[48*160];   // 30.7 KB
    int e = blockIdx.x * 256 + threadIdx.x;
    int s = ei[e], d = ei[NE + e];

    load_chunk<128,416>(sW2, w2, 0);

    float ea[48];
    float sh1[3];
    edge_embed(e, s, d, pos, edge_bond, em_w1, em_b1, em_w2, em_b2, ea, sh1);

    float v[12];
    {
        const float4* rs = reinterpret_cast<const float4*>(node1 + (size_t)s*28);
        const float4* rd = reinterpret_cast<const float4*>(node1 + (size_t)d*28);
        #pragma unroll
        for (int k = 0; k < 4; ++k) {
            float4 q = rs[k];
            ea[16+4*k] = q.x; ea[17+4*k] = q.y; ea[18+4*k] = q.z; ea[19+4*k] = q.w;
            float4 r = rd[k];
            ea[32+4*k] = r.x; ea[33+4*k] = r.y; ea[34+4*k] = r.z; ea[35+4*k] = r.w;
        }
        #pragma unroll
        for (int k = 0; k < 3; ++k) {
            float4 r = rd[4+k];
            v[4*k+0] = r.x; v[4*k+1] = r.y; v[4*k+2] = r.z; v[4*k+3] = r.w;
        }
    }

    float vdot[4], crs[12];
    #pragma unroll
    for (int u = 0; u < 4; ++u) {
        vdot[u] = v[u*3+0]*sh1[0] + v[u*3+1]*sh1[1] + v[u*3+2]*sh1[2];
        crs[u*3+0] = v[u*3+1]*sh1[2] - v[u*3+2]*sh1[1];
        crs[u*3+1] = v[u*3+2]*sh1[0] - v[u*3+0]*sh1[2];
        crs[u*3+2] = v[u*3+0]*sh1[1] - v[u*3+1]*sh1[0];
    }

    float h[48];
    #pragma unroll
    for (int j = 0; j < 48; ++j) h[j] = b1[j];
    #pragma unroll
    for (int t = 0; t < 48; ++t) {
        float vv = ea[t];
        #pragma unroll
        for (int j = 0; j < 48; ++j) h[j] += vv * w1[t*48 + j];
    }
    #pragma unroll
    for (int j = 0; j < 48; ++j) h[j] = frelu(h[j]);

    float out0[16];
    #pragma unroll
    for (int k = 0; k < 16; ++k) out0[k] = 0.0f;

    __syncthreads();
    compute_wa8(sW2, h, b2, node1 + (size_t)d*28, 0, out0);
    __syncthreads();
    load_chunk<128,416>(sW2, w2, 128);
    __syncthreads();
    compute_wa8(sW2, h, b2, node1 + (size_t)d*28, 8, out0);
    __syncthreads();
    load_chunk<160,416>(sW2, w2, 256);
    __syncthreads();

    // tail chunk, stride 160: [wb:0..63][wc:64..127][wd:128..143][we:144..159]
    const float INV_SQ3 = 0.5773502691896258f;
    #pragma unroll
    for (int u = 0; u < 4; ++u) {            // wb, contract with vdot (static u)
        float wk[16];
        #pragma unroll
        for (int k = 0; k < 16; ++k) wk[k] = b2[256 + u*16 + k];
        #pragma unroll
        for (int j = 0; j < 48; ++j) {
            float hv = h[j];
            const float4* wr = reinterpret_cast<const float4*>(&sW2[j*160 + u*16]);
            float4 w0 = wr[0], w1v = wr[1], w2v = wr[2], w3 = wr[3];
            wk[ 0] += hv*w0.x; wk[ 1] += hv*w0.y; wk[ 2] += hv*w0.z; wk[ 3] += hv*w0.w;
            wk[ 4] += hv*w1v.x; wk[ 5] += hv*w1v.y; wk[ 6] += hv*w1v.z; wk[ 7] += hv*w1v.w;
            wk[ 8] += hv*w2v.x; wk[ 9] += hv*w2v.y; wk[10] += hv*w2v.z; wk[11] += hv*w2v.w;
            wk[12] += hv*w3.x; wk[13] += hv*w3.y; wk[14] += hv*w3.z; wk[15] += hv*w3.w;
        }
        float vu = vdot[u] * INV_SQ3;
        #pragma unroll
        for (int k = 0; k < 16; ++k) out0[k] += vu * wk[k];
    }

    float outc[4] = {0.f, 0.f, 0.f, 0.f};
    for (int u = 0; u < 16; ++u) {           // wc, contract with s (runtime u, su via L1)
        float wq[4];
        #pragma unroll
        for (int q = 0; q < 4; ++q) wq[q] = b2[320 + u*4 + q];
        #pragma unroll
        for (int j = 0; j < 48; ++j) {
            float hv = h[j];
            const float4 w = *reinterpret_cast<const float4*>(&sW2[j*160 + 64 + u*4]);
            wq[0] += hv*w.x; wq[1] += hv*w.y; wq[2] += hv*w.z; wq[3] += hv*w.w;
        }
        float su = node1[(size_t)d*28 + u];
        #pragma unroll
        for (int q = 0; q < 4; ++q) outc[q] += su * wq[q];
    }

    float o1o[12];
    #pragma unroll
    for (int t = 0; t < 12; ++t) o1o[t] = 0.0f;
    #pragma unroll
    for (int u = 0; u < 4; ++u) {            // wd, contract with v
        float wq[4];
        #pragma unroll
        for (int q = 0; q < 4; ++q) wq[q] = b2[384 + u*4 + q];
        #pragma unroll
        for (int j = 0; j < 48; ++j) {
            float hv = h[j];
            const float4 w = *reinterpret_cast<const float4*>(&sW2[j*160 + 128 + u*4]);
            wq[0] += hv*w.x; wq[1] += hv*w.y; wq[2] += hv*w.z; wq[3] += hv*w.w;
        }
        #pragma unroll
        for (int q = 0; q < 4; ++q) {
            o1o[q*3+0] += wq[q] * v[u*3+0];
            o1o[q*3+1] += wq[q] * v[u*3+1];
            o1o[q*3+2] += wq[q] * v[u*3+2];
        }
    }

    float o1e[12];
    #pragma unroll
    for (int t = 0; t < 12; ++t) o1e[t] = 0.0f;
    #pragma unroll
    for (int u = 0; u < 4; ++u) {            // we, contract with cross(v, sh1)
        float wq[4];
        #pragma unroll
        for (int q = 0; q < 4; ++q) wq[q] = b2[400 + u*4 + q];
        #pragma unroll
        for (int j = 0; j < 48; ++j) {
            float hv = h[j];
            const float4 w = *reinterpret_cast<const float4*>(&sW2[j*160 + 144 + u*4]);
            wq[0] += hv*w.x; wq[1] += hv*w.y; wq[2] += hv*w.z; wq[3] += hv*w.w;
        }
        #pragma unroll
        for (int q = 0; q < 4; ++q) {
            o1e[q*3+0] += wq[q] * crs[u*3+0];
            o1e[q*3+1] += wq[q] * crs[u*3+1];
            o1e[q*3+2] += wq[q] * crs[u*3+2];
        }
    }

    const float A0 = 0.22360679774997896f;   // 1/sqrt(20)
    const float AE = 0.3535533905932738f;    // 0.5/sqrt(2)
    float* out = accum2 + (size_t)s * 40;
    #pragma unroll
    for (int k = 0; k < 16; ++k) atomicAdd(out + k, out0[k] * A0);
    #pragma unroll
    for (int q = 0; q < 4; ++q)
        #pragma unroll
        for (int i = 0; i < 3; ++i)
            atomicAdd(out + 16 + q*3 + i, (outc[q]*sh1[i] + o1o[q*3+i]) * A0);
    #pragma unroll
    for (int t = 0; t < 12; ++t) atomicAdd(out + 28 + t, o1e[t] * AE);
}

__global__ __launch_bounds__(256)
void k_div(const float* in, float* out, const float* __restrict__ cnt, int cols, int total)
{
    int i = blockIdx.x * 256 + threadIdx.x;
    if (i >= total) return;
    int n = i / cols;
    out[i] = in[i] / fmaxf(cnt[n], 1.0f);
}

extern "C" void kernel_launch(void* const* d_in, const int* in_sizes, int n_in,
                              void* d_out, int out_size, void* d_ws, size_t ws_size,
                              hipStream_t stream) {
    const int*   x_cat     = (const int*)  d_in[0];
    const float* x_scalar  = (const float*)d_in[1];
    const float* pos       = (const float*)d_in[2];
    const int*   ei        = (const int*)  d_in[3];
    const float* edge_bond = (const float*)d_in[4];
    const float* emb       = (const float*)d_in[5];
    const float* node_w    = (const float*)d_in[6];
    const float* node_b    = (const float*)d_in[7];
    const float* em_w1     = (const float*)d_in[8];
    const float* em_b1     = (const float*)d_in[9];
    const float* em_w2     = (const float*)d_in[10];
    const float* em_b2     = (const float*)d_in[11];
    const float* c1_w1     = (const float*)d_in[12];
    const float* c1_b1     = (const float*)d_in[13];
    const float* c1_w2     = (const float*)d_in[14];
    const float* c1_b2     = (const float*)d_in[15];
    const float* c2_w1     = (const float*)d_in[16];
    const float* c2_b1     = (const float*)d_in[17];
    const float* c2_w2     = (const float*)d_in[18];
    const float* c2_b2     = (const float*)d_in[19];

    float* ws     = (float*)d_ws;
    float* node0  = ws;                  // NN*16 = 320000
    float* accum1 = ws + 320000;         // NN*28 = 560000 (becomes node1 in place)
    float* accum2 = ws + 880000;         // NN*40 = 800000
    float* cnt    = ws + 1680000;        // NN    = 20000

    hipMemsetAsync(accum1, 0, (size_t)(560000 + 800000 + 20000) * sizeof(float), stream);

    k_node_feat<<<(NN + 255) / 256, 256, 0, stream>>>(
        x_cat, x_scalar, emb, node_w, node_b, node0);

    k_edge_l1<<<NE / 256, 256, 0, stream>>>(
        ei, pos, edge_bond, em_w1, em_b1, em_w2, em_b2,
        c1_w1, c1_b1, c1_w2, c1_b2, node0, accum1, cnt);

    k_div<<<(560000 + 255) / 256, 256, 0, stream>>>(accum1, accum1, cnt, 28, 560000);

    k_edge_l2<<<NE / 256, 256, 0, stream>>>(
        ei, pos, edge_bond, em_w1, em_b1, em_w2, em_b2,
        c2_w1, c2_b1, c2_w2, c2_b2, accum1, accum2);

    k_div<<<(800000 + 255) / 256, 256, 0, stream>>>(accum2, (float*)d_out, cnt, 40, 800000);
}

// Round 3
// 1835.118 us; speedup vs baseline: 2.4597x; 2.4597x over previous
//
#include <hip/hip_runtime.h>
#include <math.h>

#define NN 20000
#define NE 320000

static_assert(NE % 512 == 0, "2-edge blocks must tile exactly");

__device__ __forceinline__ float frelu(float x){ return fmaxf(x, 0.0f); }

// Geometry + distance embedding + edge MLP input vector. Fills eemb[16], sh1[3].
__device__ __forceinline__ void edge_embed(
    int e, int s, int d,
    const float* __restrict__ pos,
    const float* __restrict__ edge_bond,
    const float* __restrict__ em_w1, const float* __restrict__ em_b1,
    const float* __restrict__ em_w2, const float* __restrict__ em_b2,
    float* eemb, float* sh1)
{
    float vx = pos[d*3+0] - pos[s*3+0];
    float vy = pos[d*3+1] - pos[s*3+1];
    float vz = pos[d*3+2] - pos[s*3+2];
    float d2 = vx*vx + vy*vy + vz*vz + 1e-12f;
    float dist = sqrtf(d2);
    float inv = 1.0f / (dist + 1e-8f);
    const float SQ3 = 1.7320508075688772f;
    sh1[0] = SQ3 * vx * inv;
    sh1[1] = SQ3 * vy * inv;
    sh1[2] = SQ3 * vz * inv;

    float ein[42];
    #pragma unroll
    for (int t = 0; t < 10; ++t) ein[t] = edge_bond[e*10 + t];
    const float coeff = -19.22f;            // -0.5 / (5/31)^2
    const float step  = 5.0f / 31.0f;
    #pragma unroll
    for (int k = 0; k < 32; ++k) {
        float dd = dist - step * (float)k;
        ein[10+k] = __expf(coeff * dd * dd);
    }

    float t1[16];
    #pragma unroll
    for (int j = 0; j < 16; ++j) t1[j] = em_b1[j];
    #pragma unroll
    for (int t = 0; t < 42; ++t) {
        float v = ein[t];
        #pragma unroll
        for (int j = 0; j < 16; ++j) t1[j] += v * em_w1[t*16 + j];
    }
    #pragma unroll
    for (int j = 0; j < 16; ++j) t1[j] = frelu(t1[j]);

    #pragma unroll
    for (int j = 0; j < 16; ++j) eemb[j] = em_b2[j];
    #pragma unroll
    for (int t = 0; t < 16; ++t) {
        float v = t1[t];
        #pragma unroll
        for (int j = 0; j < 16; ++j) eemb[j] += v * em_w2[t*16 + j];
    }
}

// Per-edge hidden vector h = relu([edge_emb, node_s[:16], node_d[:16]] @ W1 + b1).
// W1/b1 reads are lane-uniform -> s_load broadcast (0 VGPR cost).
template<int STRIDE>
__device__ __forceinline__ void compute_h(
    int e, int s, int d,
    const float* __restrict__ pos, const float* __restrict__ edge_bond,
    const float* __restrict__ em_w1, const float* __restrict__ em_b1,
    const float* __restrict__ em_w2, const float* __restrict__ em_b2,
    const float* __restrict__ w1, const float* __restrict__ b1,
    const float* __restrict__ node, float* h, float* sh1)
{
    float ea[48];
    edge_embed(e, s, d, pos, edge_bond, em_w1, em_b1, em_w2, em_b2, ea, sh1);
    const float4* rs = reinterpret_cast<const float4*>(node + (size_t)s*STRIDE);
    const float4* rd = reinterpret_cast<const float4*>(node + (size_t)d*STRIDE);
    #pragma unroll
    for (int k = 0; k < 4; ++k) {
        float4 q = rs[k];
        ea[16+4*k] = q.x; ea[17+4*k] = q.y; ea[18+4*k] = q.z; ea[19+4*k] = q.w;
        float4 r = rd[k];
        ea[32+4*k] = r.x; ea[33+4*k] = r.y; ea[34+4*k] = r.z; ea[35+4*k] = r.w;
    }
    #pragma unroll
    for (int j = 0; j < 48; ++j) h[j] = b1[j];
    #pragma unroll
    for (int t = 0; t < 48; ++t) {
        float v = ea[t];
        #pragma unroll
        for (int j = 0; j < 48; ++j) h[j] += v * w1[t*48 + j];
    }
    #pragma unroll
    for (int j = 0; j < 48; ++j) h[j] = frelu(h[j]);
}

__global__ __launch_bounds__(256)
void k_node_feat(const int* __restrict__ x_cat, const float* __restrict__ x_scalar,
                 const float* __restrict__ emb, const float* __restrict__ node_w,
                 const float* __restrict__ node_b, float* __restrict__ node0)
{
    int n = blockIdx.x * 256 + threadIdx.x;
    if (n >= NN) return;
    float acc[16];
    #pragma unroll
    for (int k = 0; k < 16; ++k) acc[k] = node_b[k];
    #pragma unroll
    for (int c = 0; c < 10; ++c) {
        int idx = x_cat[n*10 + c];
        const float4* row = reinterpret_cast<const float4*>(emb + (c*119 + idx)*16);
        #pragma unroll
        for (int k = 0; k < 4; ++k) {
            float4 q = row[k];
            acc[4*k+0] += q.x; acc[4*k+1] += q.y; acc[4*k+2] += q.z; acc[4*k+3] += q.w;
        }
    }
    #pragma unroll
    for (int t = 0; t < 32; ++t) {
        float xs = x_scalar[n*32 + t];
        #pragma unroll
        for (int k = 0; k < 16; ++k) acc[k] += xs * node_w[t*16 + k];
    }
    #pragma unroll
    for (int k = 0; k < 16; ++k) node0[n*16 + k] = acc[k];
}

// Layer 1: 2 edges per thread, weights streamed via s_load, su folded into h.
__global__ __launch_bounds__(256)
void k_edge_l1(const int* __restrict__ ei, const float* __restrict__ pos,
               const float* __restrict__ edge_bond,
               const float* __restrict__ em_w1, const float* __restrict__ em_b1,
               const float* __restrict__ em_w2, const float* __restrict__ em_b2,
               const float* __restrict__ w1, const float* __restrict__ b1,
               const float* __restrict__ w2, const float* __restrict__ b2,
               const float* __restrict__ node0,
               float* __restrict__ accum, float* __restrict__ cnt)
{
    int base = blockIdx.x * 512 + threadIdx.x;
    int eA = base, eB = base + 256;
    int sa = ei[eA], da = ei[NE + eA];
    int sb = ei[eB], db = ei[NE + eB];

    float h_a[48], sh1a[3];
    compute_h<16>(eA, sa, da, pos, edge_bond, em_w1, em_b1, em_w2, em_b2, w1, b1, node0, h_a, sh1a);
    float h_b[48], sh1b[3];
    compute_h<16>(eB, sb, db, pos, edge_bond, em_w1, em_b1, em_w2, em_b2, w1, b1, node0, h_b, sh1b);

    const float* rda = node0 + da*16;
    const float* rdb = node0 + db*16;

    float out0a[16], out0b[16], oba[4], obb[4];
    #pragma unroll
    for (int k = 0; k < 16; ++k) { out0a[k] = 0.f; out0b[k] = 0.f; }
    #pragma unroll
    for (int q = 0; q < 4; ++q) { oba[q] = 0.f; obb[q] = 0.f; }

    for (int u = 0; u < 16; ++u) {
        float sua = rda[u], sub = rdb[u];
        #pragma unroll
        for (int k = 0; k < 16; ++k) {
            float bb = b2[u*16 + k];
            out0a[k] += sua * bb; out0b[k] += sub * bb;
        }
        #pragma unroll
        for (int q = 0; q < 4; ++q) {
            float bb = b2[256 + u*4 + q];
            oba[q] += sua * bb; obb[q] += sub * bb;
        }
        #pragma unroll
        for (int j = 0; j < 48; ++j) {
            float ha = h_a[j] * sua, hb = h_b[j] * sub;
            #pragma unroll
            for (int k = 0; k < 16; ++k) {
                float w = w2[j*320 + u*16 + k];
                out0a[k] += ha * w; out0b[k] += hb * w;
            }
            #pragma unroll
            for (int q = 0; q < 4; ++q) {
                float w = w2[j*320 + 256 + u*4 + q];
                oba[q] += ha * w; obb[q] += hb * w;
            }
        }
    }

    const float a = 0.25f;                     // 1/sqrt(16)
    {
        float* out = accum + (size_t)sa * 28;
        #pragma unroll
        for (int k = 0; k < 16; ++k) atomicAdd(out + k, out0a[k] * a);
        #pragma unroll
        for (int q = 0; q < 4; ++q)
            #pragma unroll
            for (int i = 0; i < 3; ++i)
                atomicAdd(out + 16 + q*3 + i, oba[q] * a * sh1a[i]);
        atomicAdd(cnt + sa, 1.0f);
    }
    {
        float* out = accum + (size_t)sb * 28;
        #pragma unroll
        for (int k = 0; k < 16; ++k) atomicAdd(out + k, out0b[k] * a);
        #pragma unroll
        for (int q = 0; q < 4; ++q)
            #pragma unroll
            for (int i = 0; i < 3; ++i)
                atomicAdd(out + 16 + q*3 + i, obb[q] * a * sh1b[i]);
        atomicAdd(cnt + sb, 1.0f);
    }
}

// Layer 2: 2 edges per thread; out0 flushed before wd/we tail to cap VGPR peak.
__global__ __launch_bounds__(256)
void k_edge_l2(const int* __restrict__ ei, const float* __restrict__ pos,
               const float* __restrict__ edge_bond,
               const float* __restrict__ em_w1, const float* __restrict__ em_b1,
               const float* __restrict__ em_w2, const float* __restrict__ em_b2,
               const float* __restrict__ w1, const float* __restrict__ b1,
               const float* __restrict__ w2, const float* __restrict__ b2,
               const float* __restrict__ node1,
               float* __restrict__ accum2)
{
    int base = blockIdx.x * 512 + threadIdx.x;
    int eA = base, eB = base + 256;
    int sa = ei[eA], da = ei[NE + eA];
    int sb = ei[eB], db = ei[NE + eB];

    float h_a[48], sh1a[3];
    compute_h<28>(eA, sa, da, pos, edge_bond, em_w1, em_b1, em_w2, em_b2, w1, b1, node1, h_a, sh1a);
    float h_b[48], sh1b[3];
    compute_h<28>(eB, sb, db, pos, edge_bond, em_w1, em_b1, em_w2, em_b2, w1, b1, node1, h_b, sh1b);

    const float* rda = node1 + (size_t)da * 28;
    const float* rdb = node1 + (size_t)db * 28;

    float vdota[4], vdotb[4];
    #pragma unroll
    for (int u = 0; u < 4; ++u) {
        vdota[u] = rda[16+u*3]*sh1a[0] + rda[16+u*3+1]*sh1a[1] + rda[16+u*3+2]*sh1a[2];
        vdotb[u] = rdb[16+u*3]*sh1b[0] + rdb[16+u*3+1]*sh1b[1] + rdb[16+u*3+2]*sh1b[2];
    }

    float out0a[16], out0b[16], outca[4], outcb[4];
    #pragma unroll
    for (int k = 0; k < 16; ++k) { out0a[k] = 0.f; out0b[k] = 0.f; }
    #pragma unroll
    for (int q = 0; q < 4; ++q) { outca[q] = 0.f; outcb[q] = 0.f; }

    // wa (cols u*16+k, contract s) + wc (cols 320+u*4+q, contract s)
    for (int u = 0; u < 16; ++u) {
        float sua = rda[u], sub = rdb[u];
        #pragma unroll
        for (int k = 0; k < 16; ++k) {
            float bb = b2[u*16 + k];
            out0a[k] += sua * bb; out0b[k] += sub * bb;
        }
        #pragma unroll
        for (int q = 0; q < 4; ++q) {
            float bb = b2[320 + u*4 + q];
            outca[q] += sua * bb; outcb[q] += sub * bb;
        }
        #pragma unroll
        for (int j = 0; j < 48; ++j) {
            float ha = h_a[j] * sua, hb = h_b[j] * sub;
            #pragma unroll
            for (int k = 0; k < 16; ++k) {
                float w = w2[j*416 + u*16 + k];
                out0a[k] += ha * w; out0b[k] += hb * w;
            }
            #pragma unroll
            for (int q = 0; q < 4; ++q) {
                float w = w2[j*416 + 320 + u*4 + q];
                outca[q] += ha * w; outcb[q] += hb * w;
            }
        }
    }

    // wb (cols 256+u*16+k, contract vdot/sqrt3)
    const float INV_SQ3 = 0.5773502691896258f;
    #pragma unroll
    for (int u = 0; u < 4; ++u) {
        float va = vdota[u] * INV_SQ3, vb = vdotb[u] * INV_SQ3;
        #pragma unroll
        for (int k = 0; k < 16; ++k) {
            float bb = b2[256 + u*16 + k];
            out0a[k] += va * bb; out0b[k] += vb * bb;
        }
        #pragma unroll
        for (int j = 0; j < 48; ++j) {
            float ha = h_a[j] * va, hb = h_b[j] * vb;
            #pragma unroll
            for (int k = 0; k < 16; ++k) {
                float w = w2[j*416 + 256 + u*16 + k];
                out0a[k] += ha * w; out0b[k] += hb * w;
            }
        }
    }

    const float A0 = 0.22360679774997896f;   // 1/sqrt(20)
    {   // flush scalar outputs now -> frees 32 VGPRs for the tail
        float* out = accum2 + (size_t)sa * 40;
        #pragma unroll
        for (int k = 0; k < 16; ++k) atomicAdd(out + k, out0a[k] * A0);
    }
    {
        float* out = accum2 + (size_t)sb * 40;
        #pragma unroll
        for (int k = 0; k < 16; ++k) atomicAdd(out + k, out0b[k] * A0);
    }

    // wd (cols 384+u*4+q, contract v) + we (cols 400+u*4+q, contract cross(v,sh1))
    float o1oa[12], o1ob[12], o1ea[12], o1eb[12];
    #pragma unroll
    for (int t = 0; t < 12; ++t) { o1oa[t]=0.f; o1ob[t]=0.f; o1ea[t]=0.f; o1eb[t]=0.f; }

    #pragma unroll
    for (int u = 0; u < 4; ++u) {
        float wda[4], wdb[4], wea[4], web[4];
        #pragma unroll
        for (int q = 0; q < 4; ++q) {
            wda[q] = b2[384 + u*4 + q]; wdb[q] = wda[q];
            wea[q] = b2[400 + u*4 + q]; web[q] = wea[q];
        }
        #pragma unroll
        for (int j = 0; j < 48; ++j) {
            float hva = h_a[j], hvb = h_b[j];
            #pragma unroll
            for (int q = 0; q < 4; ++q) {
                float w = w2[j*416 + 384 + u*4 + q];
                wda[q] += hva * w; wdb[q] += hvb * w;
            }
            #pragma unroll
            for (int q = 0; q < 4; ++q) {
                float w = w2[j*416 + 400 + u*4 + q];
                wea[q] += hva * w; web[q] += hvb * w;
            }
        }
        float vax = rda[16+u*3], vay = rda[16+u*3+1], vaz = rda[16+u*3+2];
        float vbx = rdb[16+u*3], vby = rdb[16+u*3+1], vbz = rdb[16+u*3+2];
        float cax = vay*sh1a[2] - vaz*sh1a[1];
        float cay = vaz*sh1a[0] - vax*sh1a[2];
        float caz = vax*sh1a[1] - vay*sh1a[0];
        float cbx = vby*sh1b[2] - vbz*sh1b[1];
        float cby = vbz*sh1b[0] - vbx*sh1b[2];
        float cbz = vbx*sh1b[1] - vby*sh1b[0];
        #pragma unroll
        for (int q = 0; q < 4; ++q) {
            o1oa[q*3+0] += wda[q]*vax; o1oa[q*3+1] += wda[q]*vay; o1oa[q*3+2] += wda[q]*vaz;
            o1ob[q*3+0] += wdb[q]*vbx; o1ob[q*3+1] += wdb[q]*vby; o1ob[q*3+2] += wdb[q]*vbz;
            o1ea[q*3+0] += wea[q]*cax; o1ea[q*3+1] += wea[q]*cay; o1ea[q*3+2] += wea[q]*caz;
            o1eb[q*3+0] += web[q]*cbx; o1eb[q*3+1] += web[q]*cby; o1eb[q*3+2] += web[q]*cbz;
        }
    }

    const float AE = 0.3535533905932738f;    // 0.5/sqrt(2)
    {
        float* out = accum2 + (size_t)sa * 40;
        #pragma unroll
        for (int q = 0; q < 4; ++q)
            #pragma unroll
            for (int i = 0; i < 3; ++i)
                atomicAdd(out + 16 + q*3 + i, (outca[q]*sh1a[i] + o1oa[q*3+i]) * A0);
        #pragma unroll
        for (int t = 0; t < 12; ++t) atomicAdd(out + 28 + t, o1ea[t] * AE);
    }
    {
        float* out = accum2 + (size_t)sb * 40;
        #pragma unroll
        for (int q = 0; q < 4; ++q)
            #pragma unroll
            for (int i = 0; i < 3; ++i)
                atomicAdd(out + 16 + q*3 + i, (outcb[q]*sh1b[i] + o1ob[q*3+i]) * A0);
        #pragma unroll
        for (int t = 0; t < 12; ++t) atomicAdd(out + 28 + t, o1eb[t] * AE);
    }
}

__global__ __launch_bounds__(256)
void k_div(const float* in, float* out, const float* __restrict__ cnt, int cols, int total)
{
    int i = blockIdx.x * 256 + threadIdx.x;
    if (i >= total) return;
    int n = i / cols;
    out[i] = in[i] / fmaxf(cnt[n], 1.0f);
}

extern "C" void kernel_launch(void* const* d_in, const int* in_sizes, int n_in,
                              void* d_out, int out_size, void* d_ws, size_t ws_size,
                              hipStream_t stream) {
    const int*   x_cat     = (const int*)  d_in[0];
    const float* x_scalar  = (const float*)d_in[1];
    const float* pos       = (const float*)d_in[2];
    const int*   ei        = (const int*)  d_in[3];
    const float* edge_bond = (const float*)d_in[4];
    const float* emb       = (const float*)d_in[5];
    const float* node_w    = (const float*)d_in[6];
    const float* node_b    = (const float*)d_in[7];
    const float* em_w1     = (const float*)d_in[8];
    const float* em_b1     = (const float*)d_in[9];
    const float* em_w2     = (const float*)d_in[10];
    const float* em_b2     = (const float*)d_in[11];
    const float* c1_w1     = (const float*)d_in[12];
    const float* c1_b1     = (const float*)d_in[13];
    const float* c1_w2     = (const float*)d_in[14];
    const float* c1_b2     = (const float*)d_in[15];
    const float* c2_w1     = (const float*)d_in[16];
    const float* c2_b1     = (const float*)d_in[17];
    const float* c2_w2     = (const float*)d_in[18];
    const float* c2_b2     = (const float*)d_in[19];

    float* ws     = (float*)d_ws;
    float* node0  = ws;                  // NN*16 = 320000
    float* accum1 = ws + 320000;         // NN*28 = 560000 (becomes node1 in place)
    float* accum2 = ws + 880000;         // NN*40 = 800000
    float* cnt    = ws + 1680000;        // NN    = 20000

    hipMemsetAsync(accum1, 0, (size_t)(560000 + 800000 + 20000) * sizeof(float), stream);

    k_node_feat<<<(NN + 255) / 256, 256, 0, stream>>>(
        x_cat, x_scalar, emb, node_w, node_b, node0);

    k_edge_l1<<<NE / 512, 256, 0, stream>>>(
        ei, pos, edge_bond, em_w1, em_b1, em_w2, em_b2,
        c1_w1, c1_b1, c1_w2, c1_b2, node0, accum1, cnt);

    k_div<<<(560000 + 255) / 256, 256, 0, stream>>>(accum1, accum1, cnt, 28, 560000);

    k_edge_l2<<<NE / 512, 256, 0, stream>>>(
        ei, pos, edge_bond, em_w1, em_b1, em_w2, em_b2,
        c2_w1, c2_b1, c2_w2, c2_b2, accum1, accum2);

    k_div<<<(800000 + 255) / 256, 256, 0, stream>>>(accum2, (float*)d_out, cnt, 40, 800000);
}

// Round 4
// 1357.868 us; speedup vs baseline: 3.3242x; 1.3515x over previous
//
#include <hip/hip_runtime.h>
#include <math.h>

#define NN 20000
#define NE 320000
#define HPAD 50   // padded h row (floats): 8B-aligned b64 reads, 2-way bank alias (free)

static_assert(NE % 256 == 0, "edge grid must tile exactly");

__device__ __forceinline__ float frelu(float x){ return fmaxf(x, 0.0f); }

// Geometry + distance embedding + edge-emb MLP (small weights via uniform s_load).
__device__ __forceinline__ void edge_embed(
    int e, int s, int d,
    const float* __restrict__ pos,
    const float* __restrict__ edge_bond,
    const float* __restrict__ em_w1, const float* __restrict__ em_b1,
    const float* __restrict__ em_w2, const float* __restrict__ em_b2,
    float* eemb, float* sh1)
{
    float vx = pos[d*3+0] - pos[s*3+0];
    float vy = pos[d*3+1] - pos[s*3+1];
    float vz = pos[d*3+2] - pos[s*3+2];
    float d2 = vx*vx + vy*vy + vz*vz + 1e-12f;
    float dist = sqrtf(d2);
    float inv = 1.0f / (dist + 1e-8f);
    const float SQ3 = 1.7320508075688772f;
    sh1[0] = SQ3 * vx * inv;
    sh1[1] = SQ3 * vy * inv;
    sh1[2] = SQ3 * vz * inv;

    float ein[42];
    #pragma unroll
    for (int t = 0; t < 10; ++t) ein[t] = edge_bond[e*10 + t];
    const float coeff = -19.22f;            // -0.5 / (5/31)^2
    const float step  = 5.0f / 31.0f;
    #pragma unroll
    for (int k = 0; k < 32; ++k) {
        float dd = dist - step * (float)k;
        ein[10+k] = __expf(coeff * dd * dd);
    }

    float t1[16];
    #pragma unroll
    for (int j = 0; j < 16; ++j) t1[j] = em_b1[j];
    #pragma unroll
    for (int t = 0; t < 42; ++t) {
        float v = ein[t];
        #pragma unroll
        for (int j = 0; j < 16; ++j) t1[j] += v * em_w1[t*16 + j];
    }
    #pragma unroll
    for (int j = 0; j < 16; ++j) t1[j] = frelu(t1[j]);

    #pragma unroll
    for (int j = 0; j < 16; ++j) eemb[j] = em_b2[j];
    #pragma unroll
    for (int t = 0; t < 16; ++t) {
        float v = t1[t];
        #pragma unroll
        for (int j = 0; j < 16; ++j) eemb[j] += v * em_w2[t*16 + j];
    }
}

// h = relu([edge_emb, node_s[:16], node_d[:16]] @ W1 + b1), fully static (registers).
template<int STRIDE>
__device__ __forceinline__ void compute_h(
    int e, int s, int d,
    const float* __restrict__ pos, const float* __restrict__ edge_bond,
    const float* __restrict__ em_w1, const float* __restrict__ em_b1,
    const float* __restrict__ em_w2, const float* __restrict__ em_b2,
    const float* __restrict__ w1, const float* __restrict__ b1,
    const float* __restrict__ node, float* h, float* sh1)
{
    float ea[48];
    edge_embed(e, s, d, pos, edge_bond, em_w1, em_b1, em_w2, em_b2, ea, sh1);
    const float4* rs = reinterpret_cast<const float4*>(node + (size_t)s*STRIDE);
    const float4* rd = reinterpret_cast<const float4*>(node + (size_t)d*STRIDE);
    #pragma unroll
    for (int k = 0; k < 4; ++k) {
        float4 q = rs[k];
        ea[16+4*k] = q.x; ea[17+4*k] = q.y; ea[18+4*k] = q.z; ea[19+4*k] = q.w;
        float4 r = rd[k];
        ea[32+4*k] = r.x; ea[33+4*k] = r.y; ea[34+4*k] = r.z; ea[35+4*k] = r.w;
    }
    #pragma unroll
    for (int j = 0; j < 48; ++j) h[j] = b1[j];
    #pragma unroll
    for (int t = 0; t < 48; ++t) {
        float v = ea[t];
        #pragma unroll
        for (int j = 0; j < 48; ++j) h[j] += v * w1[t*48 + j];
    }
    #pragma unroll
    for (int j = 0; j < 48; ++j) h[j] = frelu(h[j]);
}

// Cooperative load: 48 x C column-chunk of w2 (row stride NC) -> LDS (row-major, stride C).
template<int C, int NC>
__device__ __forceinline__ void load_chunk(float* sW, const float* __restrict__ w2, int baseCol) {
    for (int i = threadIdx.x * 4; i < 48 * C; i += 1024) {
        int j = i / C;
        int c = i - j * C;
        *reinterpret_cast<float4*>(&sW[i]) =
            *reinterpret_cast<const float4*>(&w2[j*NC + baseCol + c]);
    }
}

// o[0..15] += p * w[0..15]  (w: lane-uniform LDS broadcast, 4x ds_read_b128)
__device__ __forceinline__ void acc16(float p, const float* w, float o[16]) {
    float4 a = *reinterpret_cast<const float4*>(w+0);
    float4 b = *reinterpret_cast<const float4*>(w+4);
    float4 c = *reinterpret_cast<const float4*>(w+8);
    float4 d = *reinterpret_cast<const float4*>(w+12);
    o[ 0]+=p*a.x; o[ 1]+=p*a.y; o[ 2]+=p*a.z; o[ 3]+=p*a.w;
    o[ 4]+=p*b.x; o[ 5]+=p*b.y; o[ 6]+=p*b.z; o[ 7]+=p*b.w;
    o[ 8]+=p*c.x; o[ 9]+=p*c.y; o[10]+=p*c.z; o[11]+=p*c.w;
    o[12]+=p*d.x; o[13]+=p*d.y; o[14]+=p*d.z; o[15]+=p*d.w;
}

// out0[0..15] += mult * sum_j h[j] * sW[j][coloff..coloff+15]   (CS = chunk row stride)
template<int CS>
__device__ __forceinline__ void contract16(const float* sW, const float* sHrow,
                                           float mult, int coloff, float out0[16]) {
    #pragma unroll 2
    for (int jb = 0; jb < 12; ++jb) {
        float2 h01 = *reinterpret_cast<const float2*>(sHrow + jb*4);
        float2 h23 = *reinterpret_cast<const float2*>(sHrow + jb*4 + 2);
        const float* w = sW + jb*4*CS + coloff;
        acc16(h01.x*mult, w,        out0);
        acc16(h01.y*mult, w + CS,   out0);
        acc16(h23.x*mult, w + 2*CS, out0);
        acc16(h23.y*mult, w + 3*CS, out0);
    }
}

// acc[0..3] += mult * sum_j h[j] * sW[j][coloff..coloff+3]
template<int CS>
__device__ __forceinline__ void contract4(const float* sW, const float* sHrow,
                                          float mult, int coloff, float acc[4]) {
    #pragma unroll 2
    for (int jb = 0; jb < 12; ++jb) {
        float2 h01 = *reinterpret_cast<const float2*>(sHrow + jb*4);
        float2 h23 = *reinterpret_cast<const float2*>(sHrow + jb*4 + 2);
        const float* w = sW + jb*4*CS + coloff;
        float4 a = *reinterpret_cast<const float4*>(w);
        float4 b = *reinterpret_cast<const float4*>(w + CS);
        float4 c = *reinterpret_cast<const float4*>(w + 2*CS);
        float4 d = *reinterpret_cast<const float4*>(w + 3*CS);
        float p0 = h01.x*mult, p1 = h01.y*mult, p2 = h23.x*mult, p3 = h23.y*mult;
        acc[0]+=p0*a.x; acc[1]+=p0*a.y; acc[2]+=p0*a.z; acc[3]+=p0*a.w;
        acc[0]+=p1*b.x; acc[1]+=p1*b.y; acc[2]+=p1*b.z; acc[3]+=p1*b.w;
        acc[0]+=p2*c.x; acc[1]+=p2*c.y; acc[2]+=p2*c.z; acc[3]+=p2*c.w;
        acc[0]+=p3*d.x; acc[1]+=p3*d.y; acc[2]+=p3*d.z; acc[3]+=p3*d.w;
    }
}

__global__ __launch_bounds__(256)
void k_node_feat(const int* __restrict__ x_cat, const float* __restrict__ x_scalar,
                 const float* __restrict__ emb, const float* __restrict__ node_w,
                 const float* __restrict__ node_b, float* __restrict__ node0)
{
    int n = blockIdx.x * 256 + threadIdx.x;
    if (n >= NN) return;
    float acc[16];
    #pragma unroll
    for (int k = 0; k < 16; ++k) acc[k] = node_b[k];
    #pragma unroll
    for (int c = 0; c < 10; ++c) {
        int idx = x_cat[n*10 + c];
        const float4* row = reinterpret_cast<const float4*>(emb + (c*119 + idx)*16);
        #pragma unroll
        for (int k = 0; k < 4; ++k) {
            float4 q = row[k];
            acc[4*k+0] += q.x; acc[4*k+1] += q.y; acc[4*k+2] += q.z; acc[4*k+3] += q.w;
        }
    }
    #pragma unroll
    for (int t = 0; t < 32; ++t) {
        float xs = x_scalar[n*32 + t];
        #pragma unroll
        for (int k = 0; k < 16; ++k) acc[k] += xs * node_w[t*16 + k];
    }
    #pragma unroll
    for (int k = 0; k < 16; ++k) node0[n*16 + k] = acc[k];
}

__global__ __launch_bounds__(256)
void k_edge_l1(const int* __restrict__ ei, const float* __restrict__ pos,
               const float* __restrict__ edge_bond,
               const float* __restrict__ em_w1, const float* __restrict__ em_b1,
               const float* __restrict__ em_w2, const float* __restrict__ em_b2,
               const float* __restrict__ w1, const float* __restrict__ b1,
               const float* __restrict__ w2, const float* __restrict__ b2,
               const float* __restrict__ node0,
               float* __restrict__ accum, float* __restrict__ cnt)
{
    __shared__ float sH[256*HPAD];   // 51.2 KB
    __shared__ float sW[48*64];      // 12.3 KB
    int tid = threadIdx.x;
    int e = blockIdx.x*256 + tid;
    int s = ei[e], d = ei[NE + e];

    load_chunk<64,320>(sW, w2, 0);   // chunk0 in flight under h compute

    float h[48], sh1[3];
    compute_h<16>(e, s, d, pos, edge_bond, em_w1, em_b1, em_w2, em_b2, w1, b1, node0, h, sh1);
    {
        float* hr = &sH[tid*HPAD];
        #pragma unroll
        for (int t = 0; t < 24; ++t)
            *reinterpret_cast<float2*>(hr + 2*t) = make_float2(h[2*t], h[2*t+1]);
    }
    const float* sHrow = &sH[tid*HPAD];
    const float* srow  = node0 + d*16;

    float out0[16];
    #pragma unroll
    for (int k = 0; k < 16; ++k) out0[k] = 0.0f;

    __syncthreads();
    // wa: chunks 0..3 (cols 0..255), u = c*4+u4
    #pragma unroll 1
    for (int c = 0; c < 4; ++c) {
        if (c) {
            __syncthreads();
            load_chunk<64,320>(sW, w2, c*64);
            __syncthreads();
        }
        #pragma unroll 1
        for (int u4 = 0; u4 < 4; ++u4) {
            int u = c*4 + u4;
            float su = srow[u];
            #pragma unroll
            for (int k = 0; k < 16; ++k) out0[k] += su * b2[u*16 + k];
            contract16<64>(sW, sHrow, su, u4*16, out0);
        }
    }

    const float a = 0.25f;                     // 1/sqrt(16)
    float* outp = accum + (size_t)s * 28;
    #pragma unroll
    for (int k = 0; k < 16; ++k) atomicAdd(outp + k, out0[k] * a);

    // wb: chunk 4 (cols 256..319), wb[u,q] at offset u*4+q
    __syncthreads();
    load_chunk<64,320>(sW, w2, 256);
    __syncthreads();
    float ob[4] = {0.f, 0.f, 0.f, 0.f};
    #pragma unroll 1
    for (int u = 0; u < 16; ++u) {
        float su = srow[u];
        #pragma unroll
        for (int q = 0; q < 4; ++q) ob[q] += su * b2[256 + u*4 + q];
        contract4<64>(sW, sHrow, su, u*4, ob);
    }
    #pragma unroll
    for (int q = 0; q < 4; ++q)
        #pragma unroll
        for (int i = 0; i < 3; ++i)
            atomicAdd(outp + 16 + q*3 + i, ob[q] * a * sh1[i]);
    atomicAdd(cnt + s, 1.0f);
}

__global__ __launch_bounds__(256)
void k_edge_l2(const int* __restrict__ ei, const float* __restrict__ pos,
               const float* __restrict__ edge_bond,
               const float* __restrict__ em_w1, const float* __restrict__ em_b1,
               const float* __restrict__ em_w2, const float* __restrict__ em_b2,
               const float* __restrict__ w1, const float* __restrict__ b1,
               const float* __restrict__ w2, const float* __restrict__ b2,
               const float* __restrict__ node1,
               float* __restrict__ accum2)
{
    __shared__ float sH[256*HPAD];
    __shared__ float sW[48*64];
    int tid = threadIdx.x;
    int e = blockIdx.x*256 + tid;
    int s = ei[e], d = ei[NE + e];

    load_chunk<64,416>(sW, w2, 0);

    float h[48], sh1[3];
    compute_h<28>(e, s, d, pos, edge_bond, em_w1, em_b1, em_w2, em_b2, w1, b1, node1, h, sh1);
    {
        float* hr = &sH[tid*HPAD];
        #pragma unroll
        for (int t = 0; t < 24; ++t)
            *reinterpret_cast<float2*>(hr + 2*t) = make_float2(h[2*t], h[2*t+1]);
    }
    const float* sHrow = &sH[tid*HPAD];
    const float* rd    = node1 + (size_t)d * 28;

    float out0[16];
    #pragma unroll
    for (int k = 0; k < 16; ++k) out0[k] = 0.0f;

    __syncthreads();
    // wa: chunks 0..3 (cols 0..255)
    #pragma unroll 1
    for (int c = 0; c < 4; ++c) {
        if (c) {
            __syncthreads();
            load_chunk<64,416>(sW, w2, c*64);
            __syncthreads();
        }
        #pragma unroll 1
        for (int u4 = 0; u4 < 4; ++u4) {
            int u = c*4 + u4;
            float su = rd[u];
            #pragma unroll
            for (int k = 0; k < 16; ++k) out0[k] += su * b2[u*16 + k];
            contract16<64>(sW, sHrow, su, u4*16, out0);
        }
    }

    // wb: chunk 4 (cols 256..319), contract with vdot/sqrt3
    __syncthreads();
    load_chunk<64,416>(sW, w2, 256);
    __syncthreads();
    const float INV_SQ3 = 0.5773502691896258f;
    #pragma unroll 1
    for (int u4 = 0; u4 < 4; ++u4) {
        float vx = rd[16+u4*3], vy = rd[17+u4*3], vz = rd[18+u4*3];
        float vdu = (vx*sh1[0] + vy*sh1[1] + vz*sh1[2]) * INV_SQ3;
        #pragma unroll
        for (int k = 0; k < 16; ++k) out0[k] += vdu * b2[256 + u4*16 + k];
        contract16<64>(sW, sHrow, vdu, u4*16, out0);
    }

    const float A0 = 0.22360679774997896f;   // 1/sqrt(20)
    float* outp = accum2 + (size_t)s * 40;
    #pragma unroll
    for (int k = 0; k < 16; ++k) atomicAdd(outp + k, out0[k] * A0);

    // wc: chunk 5 (cols 320..383), wc[u,q] at offset u*4+q, contract s
    __syncthreads();
    load_chunk<64,416>(sW, w2, 320);
    __syncthreads();
    float outc[4] = {0.f, 0.f, 0.f, 0.f};
    #pragma unroll 1
    for (int u = 0; u < 16; ++u) {
        float su = rd[u];
        #pragma unroll
        for (int q = 0; q < 4; ++q) outc[q] += su * b2[320 + u*4 + q];
        contract4<64>(sW, sHrow, su, u*4, outc);
    }

    // wd+we: chunk 6 (cols 384..415, C=32): wd offset u*4, we offset 16+u*4
    __syncthreads();
    load_chunk<32,416>(sW, w2, 384);
    __syncthreads();
    float o1o[12], o1e[12];
    #pragma unroll
    for (int t = 0; t < 12; ++t) { o1o[t] = 0.f; o1e[t] = 0.f; }
    #pragma unroll
    for (int u4 = 0; u4 < 4; ++u4) {         // full unroll: o1o/o1e static
        float vx = rd[16+u4*3], vy = rd[17+u4*3], vz = rd[18+u4*3];
        float wdv[4], wev[4];
        #pragma unroll
        for (int q = 0; q < 4; ++q) {
            wdv[q] = b2[384 + u4*4 + q];
            wev[q] = b2[400 + u4*4 + q];
        }
        contract4<32>(sW, sHrow, 1.0f, u4*4,      wdv);
        contract4<32>(sW, sHrow, 1.0f, 16 + u4*4, wev);
        float cx = vy*sh1[2] - vz*sh1[1];
        float cy = vz*sh1[0] - vx*sh1[2];
        float cz = vx*sh1[1] - vy*sh1[0];
        #pragma unroll
        for (int q = 0; q < 4; ++q) {
            o1o[q*3+0] += wdv[q]*vx; o1o[q*3+1] += wdv[q]*vy; o1o[q*3+2] += wdv[q]*vz;
            o1e[q*3+0] += wev[q]*cx; o1e[q*3+1] += wev[q]*cy; o1e[q*3+2] += wev[q]*cz;
        }
    }

    const float AE = 0.3535533905932738f;    // 0.5/sqrt(2)
    #pragma unroll
    for (int q = 0; q < 4; ++q)
        #pragma unroll
        for (int i = 0; i < 3; ++i)
            atomicAdd(outp + 16 + q*3 + i, (outc[q]*sh1[i] + o1o[q*3+i]) * A0);
    #pragma unroll
    for (int t = 0; t < 12; ++t) atomicAdd(outp + 28 + t, o1e[t] * AE);
}

__global__ __launch_bounds__(256)
void k_div(const float* in, float* out, const float* __restrict__ cnt, int cols, int total)
{
    int i = blockIdx.x * 256 + threadIdx.x;
    if (i >= total) return;
    int n = i / cols;
    out[i] = in[i] / fmaxf(cnt[n], 1.0f);
}

extern "C" void kernel_launch(void* const* d_in, const int* in_sizes, int n_in,
                              void* d_out, int out_size, void* d_ws, size_t ws_size,
                              hipStream_t stream) {
    const int*   x_cat     = (const int*)  d_in[0];
    const float* x_scalar  = (const float*)d_in[1];
    const float* pos       = (const float*)d_in[2];
    const int*   ei        = (const int*)  d_in[3];
    const float* edge_bond = (const float*)d_in[4];
    const float* emb       = (const float*)d_in[5];
    const float* node_w    = (const float*)d_in[6];
    const float* node_b    = (const float*)d_in[7];
    const float* em_w1     = (const float*)d_in[8];
    const float* em_b1     = (const float*)d_in[9];
    const float* em_w2     = (const float*)d_in[10];
    const float* em_b2     = (const float*)d_in[11];
    const float* c1_w1     = (const float*)d_in[12];
    const float* c1_b1     = (const float*)d_in[13];
    const float* c1_w2     = (const float*)d_in[14];
    const float* c1_b2     = (const float*)d_in[15];
    const float* c2_w1     = (const float*)d_in[16];
    const float* c2_b1     = (const float*)d_in[17];
    const float* c2_w2     = (const float*)d_in[18];
    const float* c2_b2     = (const float*)d_in[19];

    float* ws     = (float*)d_ws;
    float* node0  = ws;                  // NN*16 = 320000
    float* accum1 = ws + 320000;         // NN*28 = 560000 (becomes node1 in place)
    float* accum2 = ws + 880000;         // NN*40 = 800000
    float* cnt    = ws + 1680000;        // NN    = 20000

    hipMemsetAsync(accum1, 0, (size_t)(560000 + 800000 + 20000) * sizeof(float), stream);

    k_node_feat<<<(NN + 255) / 256, 256, 0, stream>>>(
        x_cat, x_scalar, emb, node_w, node_b, node0);

    k_edge_l1<<<NE / 256, 256, 0, stream>>>(
        ei, pos, edge_bond, em_w1, em_b1, em_w2, em_b2,
        c1_w1, c1_b1, c1_w2, c1_b2, node0, accum1, cnt);

    k_div<<<(560000 + 255) / 256, 256, 0, stream>>>(accum1, accum1, cnt, 28, 560000);

    k_edge_l2<<<NE / 256, 256, 0, stream>>>(
        ei, pos, edge_bond, em_w1, em_b1, em_w2, em_b2,
        c2_w1, c2_b1, c2_w2, c2_b2, accum1, accum2);

    k_div<<<(800000 + 255) / 256, 256, 0, stream>>>(accum2, (float*)d_out, cnt, 40, 800000);
}

// Round 5
// 341.467 us; speedup vs baseline: 13.2188x; 3.9766x over previous
//
#include <hip/hip_runtime.h>
#include <math.h>

#define NN 20000
#define NE 320000

typedef _Float16 f16x8 __attribute__((ext_vector_type(8)));
typedef float f32x4 __attribute__((ext_vector_type(4)));
typedef unsigned short ushort_t;
typedef unsigned int uint_t;

#define MFMA16(A,B,C) __builtin_amdgcn_mfma_f32_16x16x32_f16((A),(B),(C),0,0,0)
#define LDS_FENCE() do{ asm volatile("s_waitcnt lgkmcnt(0)" ::: "memory"); __builtin_amdgcn_sched_barrier(0);}while(0)

static_assert(NE % 256 == 0, "edge grid must tile exactly");

__device__ __forceinline__ float frelu(float x){ return fmaxf(x, 0.0f); }

// split x = hi + lo * 2^-11  (lo stored pre-scaled by 2^11 to stay f16-normal)
__device__ __forceinline__ void splitf(float x, ushort_t& h, ushort_t& l){
    _Float16 hh = (_Float16)x;
    float r = (x - (float)hh) * 2048.0f;
    _Float16 ll = (_Float16)r;
    union { _Float16 f; ushort_t u; } ch, cl;
    ch.f = hh; cl.f = ll;
    h = ch.u; l = cl.u;
}

// Geometry + distance embedding + edge-emb MLP (small weights: uniform s_load).
__device__ __forceinline__ void edge_embed(
    int e, int s, int d,
    const float* __restrict__ pos,
    const float* __restrict__ edge_bond,
    const float* __restrict__ em_w1, const float* __restrict__ em_b1,
    const float* __restrict__ em_w2, const float* __restrict__ em_b2,
    float* eemb, float* sh1)
{
    float vx = pos[d*3+0] - pos[s*3+0];
    float vy = pos[d*3+1] - pos[s*3+1];
    float vz = pos[d*3+2] - pos[s*3+2];
    float d2 = vx*vx + vy*vy + vz*vz + 1e-12f;
    float dist = sqrtf(d2);
    float inv = 1.0f / (dist + 1e-8f);
    const float SQ3 = 1.7320508075688772f;
    sh1[0] = SQ3 * vx * inv;
    sh1[1] = SQ3 * vy * inv;
    sh1[2] = SQ3 * vz * inv;

    float ein[42];
    #pragma unroll
    for (int t = 0; t < 10; ++t) ein[t] = edge_bond[e*10 + t];
    const float coeff = -19.22f;            // -0.5 / (5/31)^2
    const float step  = 5.0f / 31.0f;
    #pragma unroll
    for (int k = 0; k < 32; ++k) {
        float dd = dist - step * (float)k;
        ein[10+k] = __expf(coeff * dd * dd);
    }

    float t1[16];
    #pragma unroll
    for (int j = 0; j < 16; ++j) t1[j] = em_b1[j];
    #pragma unroll
    for (int t = 0; t < 42; ++t) {
        float v = ein[t];
        #pragma unroll
        for (int j = 0; j < 16; ++j) t1[j] += v * em_w1[t*16 + j];
    }
    #pragma unroll
    for (int j = 0; j < 16; ++j) t1[j] = frelu(t1[j]);

    #pragma unroll
    for (int j = 0; j < 16; ++j) eemb[j] = em_b2[j];
    #pragma unroll
    for (int t = 0; t < 16; ++t) {
        float v = t1[t];
        #pragma unroll
        for (int j = 0; j < 16; ++j) eemb[j] += v * em_w2[t*16 + j];
    }
}

// h = relu([edge_emb, node_s[:16], node_d[:16]] @ W1 + b1); also exports node_d[:16].
template<int STRIDE>
__device__ __forceinline__ void compute_h(
    int e, int s, int d,
    const float* __restrict__ pos, const float* __restrict__ edge_bond,
    const float* __restrict__ em_w1, const float* __restrict__ em_b1,
    const float* __restrict__ em_w2, const float* __restrict__ em_b2,
    const float* __restrict__ w1, const float* __restrict__ b1,
    const float* __restrict__ node, float* h, float* sh1, float* sdout)
{
    float ea[48];
    edge_embed(e, s, d, pos, edge_bond, em_w1, em_b1, em_w2, em_b2, ea, sh1);
    const float4* rs = reinterpret_cast<const float4*>(node + (size_t)s*STRIDE);
    const float4* rd = reinterpret_cast<const float4*>(node + (size_t)d*STRIDE);
    #pragma unroll
    for (int k = 0; k < 4; ++k) {
        float4 q = rs[k];
        ea[16+4*k] = q.x; ea[17+4*k] = q.y; ea[18+4*k] = q.z; ea[19+4*k] = q.w;
        float4 r = rd[k];
        ea[32+4*k] = r.x; ea[33+4*k] = r.y; ea[34+4*k] = r.z; ea[35+4*k] = r.w;
    }
    #pragma unroll
    for (int k = 0; k < 16; ++k) sdout[k] = ea[32+k];
    #pragma unroll
    for (int j = 0; j < 48; ++j) h[j] = b1[j];
    #pragma unroll
    for (int t = 0; t < 48; ++t) {
        float v = ea[t];
        #pragma unroll
        for (int j = 0; j < 48; ++j) h[j] += v * w1[t*48 + j];
    }
    #pragma unroll
    for (int j = 0; j < 48; ++j) h[j] = frelu(h[j]);
}

// Cooperative pack of W2' (K=49 rows incl bias, zero-pad to 64) into LDS f16 hi/lo
// fragment layout: [tile_local][kb][hl][lane*8 ushorts]. One slot = (tl, kb, lane).
template<int NC>
__device__ __forceinline__ void stage_B(ushort_t* sB,
                                        const float* __restrict__ w2,
                                        const float* __restrict__ b2,
                                        int t0, int ntl, int tid)
{
    int nslots = ntl << 7;
    for (int slot = tid; slot < nslots; slot += 256) {
        int tl = slot >> 7; int r7 = slot & 127; int kb = r7 >> 6; int ll = r7 & 63;
        int col = (t0 + tl)*16 + (ll & 15);
        int k0 = (kb<<5) + ((ll>>4)<<3);
        uint_t hw[4], lw[4];
        #pragma unroll
        for (int p = 0; p < 4; ++p) {
            int ka = k0 + 2*p, kb2 = k0 + 2*p + 1;
            float va = (ka < 48) ? w2[ka*NC + col] : (ka == 48 ? b2[col] : 0.0f);
            float vb = (kb2 < 48) ? w2[kb2*NC + col] : (kb2 == 48 ? b2[col] : 0.0f);
            ushort_t ah, al, bh, bl;
            splitf(va, ah, al);
            splitf(vb, bh, bl);
            hw[p] = (uint_t)ah | ((uint_t)bh << 16);
            lw[p] = (uint_t)al | ((uint_t)bl << 16);
        }
        int base = tl*2048 + kb*1024 + ll*8;
        *reinterpret_cast<uint4*>(&sB[base])       = make_uint4(hw[0], hw[1], hw[2], hw[3]);
        *reinterpret_cast<uint4*>(&sB[base + 512]) = make_uint4(lw[0], lw[1], lw[2], lw[3]);
    }
}

// Per-wave A-frag staging through a 2 KB bounce region (in-wave fences only).
// hph/hpl: 25 packed pairs covering k=0..49 (k=48 -> 1.0 bias feature).
__device__ __forceinline__ void stage_A(ushort_t* bounce, int l,
                                        const uint_t* hph, const uint_t* hpl,
                                        f16x8 ahi[4][2], f16x8 alo[4][2])
{
    // zero once: covers k=50..63 slots which are never written afterwards
    *reinterpret_cast<uint4*>(&bounce[l*16])     = make_uint4(0,0,0,0);
    *reinterpret_cast<uint4*>(&bounce[l*16 + 8]) = make_uint4(0,0,0,0);
    LDS_FENCE();
    #pragma unroll
    for (int mt = 0; mt < 4; ++mt) {
        bool act = ((l >> 4) == mt);
        if (act) {
            #pragma unroll
            for (int jj = 0; jj < 25; ++jj) {
                int k = jj*2, kb = k >> 5, kk = k & 31;
                int lr = (l & 15) + ((kk >> 3) << 4);
                *reinterpret_cast<uint_t*>(&bounce[kb*512 + lr*8 + (kk & 7)]) = hph[jj];
            }
        }
        LDS_FENCE();
        ahi[mt][0] = *reinterpret_cast<const f16x8*>(&bounce[l*8]);
        ahi[mt][1] = *reinterpret_cast<const f16x8*>(&bounce[512 + l*8]);
        LDS_FENCE();
        if (act) {
            #pragma unroll
            for (int jj = 0; jj < 25; ++jj) {
                int k = jj*2, kb = k >> 5, kk = k & 31;
                int lr = (l & 15) + ((kk >> 3) << 4);
                *reinterpret_cast<uint_t*>(&bounce[kb*512 + lr*8 + (kk & 7)]) = hpl[jj];
            }
        }
        LDS_FENCE();
        alo[mt][0] = *reinterpret_cast<const f16x8*>(&bounce[l*8]);
        alo[mt][1] = *reinterpret_cast<const f16x8*>(&bounce[512 + l*8]);
        LDS_FENCE();
    }
}

__global__ __launch_bounds__(256)
void k_node_feat(const int* __restrict__ x_cat, const float* __restrict__ x_scalar,
                 const float* __restrict__ emb, const float* __restrict__ node_w,
                 const float* __restrict__ node_b, float* __restrict__ node0)
{
    int n = blockIdx.x * 256 + threadIdx.x;
    if (n >= NN) return;
    float acc[16];
    #pragma unroll
    for (int k = 0; k < 16; ++k) acc[k] = node_b[k];
    #pragma unroll
    for (int c = 0; c < 10; ++c) {
        int idx = x_cat[n*10 + c];
        const float4* row = reinterpret_cast<const float4*>(emb + (c*119 + idx)*16);
        #pragma unroll
        for (int k = 0; k < 4; ++k) {
            float4 q = row[k];
            acc[4*k+0] += q.x; acc[4*k+1] += q.y; acc[4*k+2] += q.z; acc[4*k+3] += q.w;
        }
    }
    #pragma unroll
    for (int t = 0; t < 32; ++t) {
        float xs = x_scalar[n*32 + t];
        #pragma unroll
        for (int k = 0; k < 16; ++k) acc[k] += xs * node_w[t*16 + k];
    }
    #pragma unroll
    for (int k = 0; k < 16; ++k) node0[n*16 + k] = acc[k];
}

// ---------------- Layer 1 (NC=320, 20 tiles: 16 wa + 4 wb) ----------------
__global__ __launch_bounds__(256)
void k_edge_l1(const int* __restrict__ ei, const float* __restrict__ pos,
               const float* __restrict__ edge_bond,
               const float* __restrict__ em_w1, const float* __restrict__ em_b1,
               const float* __restrict__ em_w2, const float* __restrict__ em_b2,
               const float* __restrict__ w1, const float* __restrict__ b1,
               const float* __restrict__ w2, const float* __restrict__ b2,
               const float* __restrict__ node0,
               float* __restrict__ accum, float* __restrict__ cnt)
{
    __shared__ __align__(16) ushort_t sB[7*2048];   // 28672 B
    __shared__ __align__(16) float    sT[16*260];   // 16640 B (s transposed [u][e])
    __shared__ float sSh[256*3];                    // 3072 B
    __shared__ int   sSrc[256];                     // 1024 B

    int tid = threadIdx.x;
    int l = tid & 63;
    int cc = l & 15;
    int e = blockIdx.x*256 + tid;
    int s = ei[e], d = ei[NE + e];

    // phase 1
    float h[48], sh1[3], sd[16];
    compute_h<16>(e, s, d, pos, edge_bond, em_w1, em_b1, em_w2, em_b2, w1, b1,
                  node0, h, sh1, sd);
    atomicAdd(cnt + s, 1.0f);
    sSrc[tid] = s;
    #pragma unroll
    for (int u = 0; u < 16; ++u) sT[u*260 + tid] = sd[u];
    #pragma unroll
    for (int k = 0; k < 3; ++k) sSh[tid*3 + k] = sh1[k];

    uint_t hph[25], hpl[25];
    #pragma unroll
    for (int jj = 0; jj < 24; ++jj) {
        ushort_t ah, al, bh, bl;
        splitf(h[2*jj],   ah, al);
        splitf(h[2*jj+1], bh, bl);
        hph[jj] = (uint_t)ah | ((uint_t)bh << 16);
        hpl[jj] = (uint_t)al | ((uint_t)bl << 16);
    }
    hph[24] = 0x3C00u;  // k=48 -> 1.0 (bias feature), k=49 -> 0
    hpl[24] = 0u;

    f16x8 ahi[4][2], alo[4][2];
    stage_A(sB + (tid >> 6)*1024, l, hph, hpl, ahi, alo);

    f32x4 out0[4];
    float ob[4][4];
    #pragma unroll
    for (int mt = 0; mt < 4; ++mt) {
        out0[mt] = (f32x4){0.f,0.f,0.f,0.f};
        #pragma unroll
        for (int r = 0; r < 4; ++r) ob[mt][r] = 0.f;
    }

    for (int c0 = 0; c0 < 20; c0 += 7) {
        int ntl = (20 - c0 < 7) ? (20 - c0) : 7;
        __syncthreads();
        stage_B<320>(sB, w2, b2, c0, ntl, tid);
        __syncthreads();
        for (int tl = 0; tl < ntl; ++tl) {
            int t = c0 + tl;
            int bb = tl*2048 + l*8;
            f16x8 bh0 = *reinterpret_cast<const f16x8*>(&sB[bb]);
            f16x8 bl0 = *reinterpret_cast<const f16x8*>(&sB[bb + 512]);
            f16x8 bh1 = *reinterpret_cast<const f16x8*>(&sB[bb + 1024]);
            f16x8 bl1 = *reinterpret_cast<const f16x8*>(&sB[bb + 1536]);
            #pragma unroll
            for (int mt = 0; mt < 4; ++mt) {
                f32x4 Dh = (f32x4){0.f,0.f,0.f,0.f};
                f32x4 Dc = (f32x4){0.f,0.f,0.f,0.f};
                Dh = MFMA16(ahi[mt][0], bh0, Dh);
                Dh = MFMA16(ahi[mt][1], bh1, Dh);
                Dc = MFMA16(alo[mt][0], bh0, Dc);
                Dc = MFMA16(ahi[mt][0], bl0, Dc);
                Dc = MFMA16(alo[mt][1], bh1, Dc);
                Dc = MFMA16(ahi[mt][1], bl1, Dc);
                f32x4 D = Dh + Dc * 0.00048828125f;   // 2^-11
                int elb = (tid & 192) + (mt << 4) + ((l >> 4) << 2);
                if (t < 16) {
                    f32x4 sv = *reinterpret_cast<const f32x4*>(&sT[t*260 + elb]);
                    out0[mt] += sv * D;
                } else {
                    const float* sp = &sT[(((t-16)<<2) + (cc>>2))*260 + elb];
                    #pragma unroll
                    for (int r = 0; r < 4; ++r) ob[mt][r] += sp[r] * D[r];
                }
            }
        }
    }

    // epilogue
    #pragma unroll
    for (int mt = 0; mt < 4; ++mt) {
        int elb = (tid & 192) + (mt << 4) + ((l >> 4) << 2);
        #pragma unroll
        for (int r = 0; r < 4; ++r) {
            int el = elb + r;
            int sidx = sSrc[el];
            atomicAdd(accum + (size_t)sidx*28 + cc, out0[mt][r] * 0.25f);
            float x = ob[mt][r];
            x += __shfl_xor(x, 4); x += __shfl_xor(x, 8);
            int q = cc / 3; int i = cc - q*3;
            float xq = __shfl(x, (l & 48) | q);
            if (cc < 12)
                atomicAdd(accum + (size_t)sidx*28 + 16 + cc, 0.25f * xq * sSh[el*3 + i]);
        }
    }
}

// ---------------- Layer 2 (NC=416, 26 tiles: 16 wa + 4 wb + 4 wc + wd + we) ----------------
__global__ __launch_bounds__(256)
void k_edge_l2(const int* __restrict__ ei, const float* __restrict__ pos,
               const float* __restrict__ edge_bond,
               const float* __restrict__ em_w1, const float* __restrict__ em_b1,
               const float* __restrict__ em_w2, const float* __restrict__ em_b2,
               const float* __restrict__ w1, const float* __restrict__ b1,
               const float* __restrict__ w2, const float* __restrict__ b2,
               const float* __restrict__ node1,
               float* __restrict__ accum2)
{
    __shared__ __align__(16) ushort_t sB[8*2048];   // 32768 B
    __shared__ __align__(16) float    sT[16*260];   // 16640 B
    __shared__ __align__(16) float    sVd[4*260];   // 4160 B (vdot*INV_SQ3 [u][e])
    __shared__ float sSh[256*3];                    // 3072 B
    __shared__ int   sSrc[256];                     // 1024 B
    __shared__ int   sDst[256];                     // 1024 B

    int tid = threadIdx.x;
    int l = tid & 63;
    int cc = l & 15;
    int e = blockIdx.x*256 + tid;
    int s = ei[e], d = ei[NE + e];

    float h[48], sh1[3], sd[16];
    compute_h<28>(e, s, d, pos, edge_bond, em_w1, em_b1, em_w2, em_b2, w1, b1,
                  node1, h, sh1, sd);
    sSrc[tid] = s;
    sDst[tid] = d;
    #pragma unroll
    for (int u = 0; u < 16; ++u) sT[u*260 + tid] = sd[u];
    #pragma unroll
    for (int k = 0; k < 3; ++k) sSh[tid*3 + k] = sh1[k];
    {
        const float4* rv = reinterpret_cast<const float4*>(node1 + (size_t)d*28 + 16);
        float4 a = rv[0], b = rv[1], c = rv[2];
        float vv[12] = {a.x,a.y,a.z,a.w, b.x,b.y,b.z,b.w, c.x,c.y,c.z,c.w};
        const float INV_SQ3 = 0.5773502691896258f;
        #pragma unroll
        for (int u = 0; u < 4; ++u)
            sVd[u*260 + tid] = (vv[u*3]*sh1[0] + vv[u*3+1]*sh1[1] + vv[u*3+2]*sh1[2]) * INV_SQ3;
    }

    uint_t hph[25], hpl[25];
    #pragma unroll
    for (int jj = 0; jj < 24; ++jj) {
        ushort_t ah, al, bh, bl;
        splitf(h[2*jj],   ah, al);
        splitf(h[2*jj+1], bh, bl);
        hph[jj] = (uint_t)ah | ((uint_t)bh << 16);
        hpl[jj] = (uint_t)al | ((uint_t)bl << 16);
    }
    hph[24] = 0x3C00u;
    hpl[24] = 0u;

    f16x8 ahi[4][2], alo[4][2];
    stage_A(sB + (tid >> 6)*1024, l, hph, hpl, ahi, alo);

    const float A0 = 0.22360679774997896f;   // 1/sqrt(20)
    const float AE = 0.3535533905932738f;    // 0.5/sqrt(2)

    f32x4 out0[4];
    float outc[4][4];
    #pragma unroll
    for (int mt = 0; mt < 4; ++mt) {
        out0[mt] = (f32x4){0.f,0.f,0.f,0.f};
        #pragma unroll
        for (int r = 0; r < 4; ++r) outc[mt][r] = 0.f;
    }

    for (int c0 = 0; c0 < 26; c0 += 8) {
        int ntl = (26 - c0 < 8) ? (26 - c0) : 8;
        __syncthreads();
        stage_B<416>(sB, w2, b2, c0, ntl, tid);
        __syncthreads();
        for (int tl = 0; tl < ntl; ++tl) {
            int t = c0 + tl;
            int bb = tl*2048 + l*8;
            f16x8 bh0 = *reinterpret_cast<const f16x8*>(&sB[bb]);
            f16x8 bl0 = *reinterpret_cast<const f16x8*>(&sB[bb + 512]);
            f16x8 bh1 = *reinterpret_cast<const f16x8*>(&sB[bb + 1024]);
            f16x8 bl1 = *reinterpret_cast<const f16x8*>(&sB[bb + 1536]);
            #pragma unroll
            for (int mt = 0; mt < 4; ++mt) {
                f32x4 Dh = (f32x4){0.f,0.f,0.f,0.f};
                f32x4 Dc = (f32x4){0.f,0.f,0.f,0.f};
                Dh = MFMA16(ahi[mt][0], bh0, Dh);
                Dh = MFMA16(ahi[mt][1], bh1, Dh);
                Dc = MFMA16(alo[mt][0], bh0, Dc);
                Dc = MFMA16(ahi[mt][0], bl0, Dc);
                Dc = MFMA16(alo[mt][1], bh1, Dc);
                Dc = MFMA16(ahi[mt][1], bl1, Dc);
                f32x4 D = Dh + Dc * 0.00048828125f;
                int elb = (tid & 192) + (mt << 4) + ((l >> 4) << 2);
                if (t < 16) {                     // wa: contract s
                    f32x4 sv = *reinterpret_cast<const f32x4*>(&sT[t*260 + elb]);
                    out0[mt] += sv * D;
                } else if (t < 20) {              // wb: contract vdot/sqrt3
                    f32x4 vd = *reinterpret_cast<const f32x4*>(&sVd[(t-16)*260 + elb]);
                    out0[mt] += vd * D;
                } else if (t < 24) {              // wc: contract s -> outc[q]
                    const float* sp = &sT[(((t-20)<<2) + (cc>>2))*260 + elb];
                    #pragma unroll
                    for (int r = 0; r < 4; ++r) outc[mt][r] += sp[r] * D[r];
                } else if (t == 24) {             // wd: + combined scatter of cols 16..27
                    #pragma unroll
                    for (int r = 0; r < 4; ++r) {
                        int el = elb + r;
                        int dv = sDst[el];
                        const float* vp = node1 + (size_t)dv*28 + 16 + (cc>>2)*3;
                        float a0 = D[r]*vp[0], a1 = D[r]*vp[1], a2 = D[r]*vp[2];
                        a0 += __shfl_xor(a0,4); a0 += __shfl_xor(a0,8);
                        a1 += __shfl_xor(a1,4); a1 += __shfl_xor(a1,8);
                        a2 += __shfl_xor(a2,4); a2 += __shfl_xor(a2,8);
                        float xc = outc[mt][r];
                        xc += __shfl_xor(xc,4); xc += __shfl_xor(xc,8);
                        int q = cc / 3; int i = cc - q*3;
                        int srcl = (l & 48) | q;
                        float g0 = __shfl(a0, srcl), g1 = __shfl(a1, srcl), g2 = __shfl(a2, srcl);
                        float oo = (i==0) ? g0 : ((i==1) ? g1 : g2);
                        float xq = __shfl(xc, srcl);
                        if (cc < 12) {
                            float sh1i = sSh[el*3 + i];
                            atomicAdd(accum2 + (size_t)sSrc[el]*40 + 16 + cc,
                                      A0 * (xq * sh1i + oo));
                        }
                    }
                } else {                          // we: cross(v, sh1), cols 28..39
                    #pragma unroll
                    for (int r = 0; r < 4; ++r) {
                        int el = elb + r;
                        int dv = sDst[el];
                        const float* vp = node1 + (size_t)dv*28 + 16 + (cc>>2)*3;
                        float vx = vp[0], vy = vp[1], vz = vp[2];
                        float sx = sSh[el*3+0], sy = sSh[el*3+1], sz = sSh[el*3+2];
                        float cx = vy*sz - vz*sy;
                        float cy = vz*sx - vx*sz;
                        float cz = vx*sy - vy*sx;
                        float a0 = D[r]*cx, a1 = D[r]*cy, a2 = D[r]*cz;
                        a0 += __shfl_xor(a0,4); a0 += __shfl_xor(a0,8);
                        a1 += __shfl_xor(a1,4); a1 += __shfl_xor(a1,8);
                        a2 += __shfl_xor(a2,4); a2 += __shfl_xor(a2,8);
                        int q = cc / 3; int i = cc - q*3;
                        int srcl = (l & 48) | q;
                        float g0 = __shfl(a0, srcl), g1 = __shfl(a1, srcl), g2 = __shfl(a2, srcl);
                        float oo = (i==0) ? g0 : ((i==1) ? g1 : g2);
                        if (cc < 12)
                            atomicAdd(accum2 + (size_t)sSrc[el]*40 + 28 + cc, AE * oo);
                    }
                }
            }
        }
    }

    // out0 scatter (cols 0..15)
    #pragma unroll
    for (int mt = 0; mt < 4; ++mt) {
        int elb = (tid & 192) + (mt << 4) + ((l >> 4) << 2);
        #pragma unroll
        for (int r = 0; r < 4; ++r) {
            int el = elb + r;
            atomicAdd(accum2 + (size_t)sSrc[el]*40 + cc, out0[mt][r] * A0);
        }
    }
}

__global__ __launch_bounds__(256)
void k_div(const float* in, float* out, const float* __restrict__ cnt, int cols, int total)
{
    int i = blockIdx.x * 256 + threadIdx.x;
    if (i >= total) return;
    int n = i / cols;
    out[i] = in[i] / fmaxf(cnt[n], 1.0f);
}

extern "C" void kernel_launch(void* const* d_in, const int* in_sizes, int n_in,
                              void* d_out, int out_size, void* d_ws, size_t ws_size,
                              hipStream_t stream) {
    const int*   x_cat     = (const int*)  d_in[0];
    const float* x_scalar  = (const float*)d_in[1];
    const float* pos       = (const float*)d_in[2];
    const int*   ei        = (const int*)  d_in[3];
    const float* edge_bond = (const float*)d_in[4];
    const float* emb       = (const float*)d_in[5];
    const float* node_w    = (const float*)d_in[6];
    const float* node_b    = (const float*)d_in[7];
    const float* em_w1     = (const float*)d_in[8];
    const float* em_b1     = (const float*)d_in[9];
    const float* em_w2     = (const float*)d_in[10];
    const float* em_b2     = (const float*)d_in[11];
    const float* c1_w1     = (const float*)d_in[12];
    const float* c1_b1     = (const float*)d_in[13];
    const float* c1_w2     = (const float*)d_in[14];
    const float* c1_b2     = (const float*)d_in[15];
    const float* c2_w1     = (const float*)d_in[16];
    const float* c2_b1     = (const float*)d_in[17];
    const float* c2_w2     = (const float*)d_in[18];
    const float* c2_b2     = (const float*)d_in[19];

    float* ws     = (float*)d_ws;
    float* node0  = ws;                  // NN*16 = 320000
    float* accum1 = ws + 320000;         // NN*28 = 560000 (becomes node1 in place)
    float* accum2 = ws + 880000;         // NN*40 = 800000
    float* cnt    = ws + 1680000;        // NN    = 20000

    hipMemsetAsync(accum1, 0, (size_t)(560000 + 800000 + 20000) * sizeof(float), stream);

    k_node_feat<<<(NN + 255) / 256, 256, 0, stream>>>(
        x_cat, x_scalar, emb, node_w, node_b, node0);

    k_edge_l1<<<NE / 256, 256, 0, stream>>>(
        ei, pos, edge_bond, em_w1, em_b1, em_w2, em_b2,
        c1_w1, c1_b1, c1_w2, c1_b2, node0, accum1, cnt);

    k_div<<<(560000 + 255) / 256, 256, 0, stream>>>(accum1, accum1, cnt, 28, 560000);

    k_edge_l2<<<NE / 256, 256, 0, stream>>>(
        ei, pos, edge_bond, em_w1, em_b1, em_w2, em_b2,
        c2_w1, c2_b1, c2_w2, c2_b2, accum1, accum2);

    k_div<<<(800000 + 255) / 256, 256, 0, stream>>>(accum2, (float*)d_out, cnt, 40, 800000);
}

// Round 6
// 340.621 us; speedup vs baseline: 13.2517x; 1.0025x over previous
//
#include <hip/hip_runtime.h>
#include <math.h>

#define NN 20000
#define NE 320000

typedef _Float16 f16x8 __attribute__((ext_vector_type(8)));
typedef float f32x4 __attribute__((ext_vector_type(4)));
typedef unsigned short ushort_t;
typedef unsigned int uint_t;

#define MFMA16(A,B,C) __builtin_amdgcn_mfma_f32_16x16x32_f16((A),(B),(C),0,0,0)
#define LDS_FENCE() do{ asm volatile("s_waitcnt lgkmcnt(0)" ::: "memory"); __builtin_amdgcn_sched_barrier(0);}while(0)

static_assert(NE % 256 == 0, "edge grid must tile exactly");

__device__ __forceinline__ float frelu(float x){ return fmaxf(x, 0.0f); }

// split x = hi + lo * 2^-11  (lo stored pre-scaled by 2^11 to stay f16-normal)
__device__ __forceinline__ void splitf(float x, ushort_t& h, ushort_t& l){
    _Float16 hh = (_Float16)x;
    float r = (x - (float)hh) * 2048.0f;
    _Float16 ll = (_Float16)r;
    union { _Float16 f; ushort_t u; } ch, cl;
    ch.f = hh; cl.f = ll;
    h = ch.u; l = cl.u;
}

// Geometry + distance embedding + edge-emb MLP (small weights: uniform s_load).
__device__ __forceinline__ void edge_embed(
    int e, int s, int d,
    const float* __restrict__ pos,
    const float* __restrict__ edge_bond,
    const float* __restrict__ em_w1, const float* __restrict__ em_b1,
    const float* __restrict__ em_w2, const float* __restrict__ em_b2,
    float* eemb, float* sh1)
{
    float vx = pos[d*3+0] - pos[s*3+0];
    float vy = pos[d*3+1] - pos[s*3+1];
    float vz = pos[d*3+2] - pos[s*3+2];
    float d2 = vx*vx + vy*vy + vz*vz + 1e-12f;
    float dist = sqrtf(d2);
    float inv = 1.0f / (dist + 1e-8f);
    const float SQ3 = 1.7320508075688772f;
    sh1[0] = SQ3 * vx * inv;
    sh1[1] = SQ3 * vy * inv;
    sh1[2] = SQ3 * vz * inv;

    float ein[42];
    #pragma unroll
    for (int t = 0; t < 10; ++t) ein[t] = edge_bond[e*10 + t];
    const float coeff = -19.22f;            // -0.5 / (5/31)^2
    const float step  = 5.0f / 31.0f;
    #pragma unroll
    for (int k = 0; k < 32; ++k) {
        float dd = dist - step * (float)k;
        ein[10+k] = __expf(coeff * dd * dd);
    }

    float t1[16];
    #pragma unroll
    for (int j = 0; j < 16; ++j) t1[j] = em_b1[j];
    #pragma unroll
    for (int t = 0; t < 42; ++t) {
        float v = ein[t];
        #pragma unroll
        for (int j = 0; j < 16; ++j) t1[j] += v * em_w1[t*16 + j];
    }
    #pragma unroll
    for (int j = 0; j < 16; ++j) t1[j] = frelu(t1[j]);

    #pragma unroll
    for (int j = 0; j < 16; ++j) eemb[j] = em_b2[j];
    #pragma unroll
    for (int t = 0; t < 16; ++t) {
        float v = t1[t];
        #pragma unroll
        for (int j = 0; j < 16; ++j) eemb[j] += v * em_w2[t*16 + j];
    }
}

// h = relu([edge_emb, node_s[:16], node_d[:16]] @ W1 + b1); also exports node_d[:16].
template<int STRIDE>
__device__ __forceinline__ void compute_h(
    int e, int s, int d,
    const float* __restrict__ pos, const float* __restrict__ edge_bond,
    const float* __restrict__ em_w1, const float* __restrict__ em_b1,
    const float* __restrict__ em_w2, const float* __restrict__ em_b2,
    const float* __restrict__ w1, const float* __restrict__ b1,
    const float* __restrict__ node, float* h, float* sh1, float* sdout)
{
    float ea[48];
    edge_embed(e, s, d, pos, edge_bond, em_w1, em_b1, em_w2, em_b2, ea, sh1);
    const float4* rs = reinterpret_cast<const float4*>(node + (size_t)s*STRIDE);
    const float4* rd = reinterpret_cast<const float4*>(node + (size_t)d*STRIDE);
    #pragma unroll
    for (int k = 0; k < 4; ++k) {
        float4 q = rs[k];
        ea[16+4*k] = q.x; ea[17+4*k] = q.y; ea[18+4*k] = q.z; ea[19+4*k] = q.w;
        float4 r = rd[k];
        ea[32+4*k] = r.x; ea[33+4*k] = r.y; ea[34+4*k] = r.z; ea[35+4*k] = r.w;
    }
    #pragma unroll
    for (int k = 0; k < 16; ++k) sdout[k] = ea[32+k];
    #pragma unroll
    for (int j = 0; j < 48; ++j) h[j] = b1[j];
    #pragma unroll
    for (int t = 0; t < 48; ++t) {
        float v = ea[t];
        #pragma unroll
        for (int j = 0; j < 48; ++j) h[j] += v * w1[t*48 + j];
    }
    #pragma unroll
    for (int j = 0; j < 48; ++j) h[j] = frelu(h[j]);
}

// One-time pack of W2' (K=49 rows incl bias, zero-pad to 64) into global hi/lo
// fragment layout: tile*2048 + kb*1024 + ll*8 (+512 for lo), ushort units.
__global__ __launch_bounds__(256)
void k_pack(const float* __restrict__ w2, const float* __restrict__ b2,
            ushort_t* __restrict__ out, int NC, int ntiles)
{
    int slot = blockIdx.x*256 + threadIdx.x;
    if (slot >= ntiles*128) return;
    int tl = slot >> 7; int r7 = slot & 127; int kb = r7 >> 6; int ll = r7 & 63;
    int col = tl*16 + (ll & 15);
    int k0 = (kb<<5) + ((ll>>4)<<3);
    uint_t hw[4], lw[4];
    #pragma unroll
    for (int p = 0; p < 4; ++p) {
        int ka = k0 + 2*p, kb2 = k0 + 2*p + 1;
        float va = (ka < 48) ? w2[ka*NC + col] : (ka == 48 ? b2[col] : 0.0f);
        float vb = (kb2 < 48) ? w2[kb2*NC + col] : (kb2 == 48 ? b2[col] : 0.0f);
        ushort_t ah, al, bh, bl;
        splitf(va, ah, al);
        splitf(vb, bh, bl);
        hw[p] = (uint_t)ah | ((uint_t)bh << 16);
        lw[p] = (uint_t)al | ((uint_t)bl << 16);
    }
    int base = tl*2048 + kb*1024 + ll*8;
    *reinterpret_cast<uint4*>(&out[base])       = make_uint4(hw[0], hw[1], hw[2], hw[3]);
    *reinterpret_cast<uint4*>(&out[base + 512]) = make_uint4(lw[0], lw[1], lw[2], lw[3]);
}

// Coalesced copy of pre-packed tiles [c0, c0+ntl) into LDS.
__device__ __forceinline__ void copy_chunk(ushort_t* sB, const ushort_t* __restrict__ g,
                                           int c0, int ntl, int tid)
{
    const uint4* gp = reinterpret_cast<const uint4*>(g) + c0*256;
    uint4* sp = reinterpret_cast<uint4*>(sB);
    for (int i = tid; i < ntl*256; i += 256) sp[i] = gp[i];
}

// Per-wave A-frag staging through a 4 KB bounce (hi+lo in one pass, 2 fences/mt).
__device__ __forceinline__ void stage_A(ushort_t* bounce, int l,
                                        const uint_t* hph, const uint_t* hpl,
                                        f16x8 ahi[4][2], f16x8 alo[4][2])
{
    #pragma unroll
    for (int t = 0; t < 4; ++t)
        *reinterpret_cast<uint4*>(&bounce[l*32 + t*8]) = make_uint4(0,0,0,0);
    LDS_FENCE();
    #pragma unroll
    for (int mt = 0; mt < 4; ++mt) {
        if ((l >> 4) == mt) {
            #pragma unroll
            for (int jj = 0; jj < 25; ++jj) {
                int k = jj*2, kb = k >> 5, kk = k & 31;
                int lr = (l & 15) + ((kk >> 3) << 4);
                int off = kb*512 + lr*8 + (kk & 7);
                *reinterpret_cast<uint_t*>(&bounce[off])        = hph[jj];
                *reinterpret_cast<uint_t*>(&bounce[1024 + off]) = hpl[jj];
            }
        }
        LDS_FENCE();
        ahi[mt][0] = *reinterpret_cast<const f16x8*>(&bounce[l*8]);
        ahi[mt][1] = *reinterpret_cast<const f16x8*>(&bounce[512 + l*8]);
        alo[mt][0] = *reinterpret_cast<const f16x8*>(&bounce[1024 + l*8]);
        alo[mt][1] = *reinterpret_cast<const f16x8*>(&bounce[1536 + l*8]);
        LDS_FENCE();
    }
}

__global__ __launch_bounds__(256)
void k_node_feat(const int* __restrict__ x_cat, const float* __restrict__ x_scalar,
                 const float* __restrict__ emb, const float* __restrict__ node_w,
                 const float* __restrict__ node_b, float* __restrict__ node0)
{
    int n = blockIdx.x * 256 + threadIdx.x;
    if (n >= NN) return;
    float acc[16];
    #pragma unroll
    for (int k = 0; k < 16; ++k) acc[k] = node_b[k];
    #pragma unroll
    for (int c = 0; c < 10; ++c) {
        int idx = x_cat[n*10 + c];
        const float4* row = reinterpret_cast<const float4*>(emb + (c*119 + idx)*16);
        #pragma unroll
        for (int k = 0; k < 4; ++k) {
            float4 q = row[k];
            acc[4*k+0] += q.x; acc[4*k+1] += q.y; acc[4*k+2] += q.z; acc[4*k+3] += q.w;
        }
    }
    #pragma unroll
    for (int t = 0; t < 32; ++t) {
        float xs = x_scalar[n*32 + t];
        #pragma unroll
        for (int k = 0; k < 16; ++k) acc[k] += xs * node_w[t*16 + k];
    }
    #pragma unroll
    for (int k = 0; k < 16; ++k) node0[n*16 + k] = acc[k];
}

// ---------------- Layer 1 (20 tiles: 16 wa + 4 wb) ----------------
__global__ __launch_bounds__(256)
void k_edge_l1(const int* __restrict__ ei, const float* __restrict__ pos,
               const float* __restrict__ edge_bond,
               const float* __restrict__ em_w1, const float* __restrict__ em_b1,
               const float* __restrict__ em_w2, const float* __restrict__ em_b2,
               const float* __restrict__ w1, const float* __restrict__ b1,
               const ushort_t* __restrict__ packW,
               const float* __restrict__ node0,
               float* __restrict__ accum, float* __restrict__ cnt)
{
    __shared__ __align__(16) ushort_t sB[7*2048];   // 28672 B
    __shared__ __align__(16) float    sT[16*260];   // 16640 B (s transposed [u][e])
    __shared__ float sSh[256*3];                    // 3072 B
    __shared__ int   sSrc[256];                     // 1024 B

    int tid = threadIdx.x;
    int l = tid & 63;
    int cc = l & 15;
    int e = blockIdx.x*256 + tid;
    int s = ei[e], d = ei[NE + e];

    // phase 1
    float h[48], sh1[3], sd[16];
    compute_h<16>(e, s, d, pos, edge_bond, em_w1, em_b1, em_w2, em_b2, w1, b1,
                  node0, h, sh1, sd);
    atomicAdd(cnt + s, 1.0f);
    sSrc[tid] = s;
    #pragma unroll
    for (int u = 0; u < 16; ++u) sT[u*260 + tid] = sd[u];
    #pragma unroll
    for (int k = 0; k < 3; ++k) sSh[tid*3 + k] = sh1[k];

    uint_t hph[25], hpl[25];
    #pragma unroll
    for (int jj = 0; jj < 24; ++jj) {
        ushort_t ah, al, bh, bl;
        splitf(h[2*jj],   ah, al);
        splitf(h[2*jj+1], bh, bl);
        hph[jj] = (uint_t)ah | ((uint_t)bh << 16);
        hpl[jj] = (uint_t)al | ((uint_t)bl << 16);
    }
    hph[24] = 0x3C00u;  // k=48 -> 1.0 (bias feature), k=49 -> 0
    hpl[24] = 0u;

    f16x8 ahi[4][2], alo[4][2];
    stage_A(sB + (tid >> 6)*2048, l, hph, hpl, ahi, alo);

    f32x4 out0[4];
    float ob[4][4];
    #pragma unroll
    for (int mt = 0; mt < 4; ++mt) {
        out0[mt] = (f32x4){0.f,0.f,0.f,0.f};
        #pragma unroll
        for (int r = 0; r < 4; ++r) ob[mt][r] = 0.f;
    }

    for (int c0 = 0; c0 < 20; c0 += 7) {
        int ntl = (20 - c0 < 7) ? (20 - c0) : 7;
        __syncthreads();
        copy_chunk(sB, packW, c0, ntl, tid);
        __syncthreads();
        for (int tl = 0; tl < ntl; ++tl) {
            int t = c0 + tl;
            int bb = tl*2048 + l*8;
            f16x8 bh0 = *reinterpret_cast<const f16x8*>(&sB[bb]);
            f16x8 bl0 = *reinterpret_cast<const f16x8*>(&sB[bb + 512]);
            f16x8 bh1 = *reinterpret_cast<const f16x8*>(&sB[bb + 1024]);
            f16x8 bl1 = *reinterpret_cast<const f16x8*>(&sB[bb + 1536]);
            #pragma unroll
            for (int mt = 0; mt < 4; ++mt) {
                f32x4 Dh = (f32x4){0.f,0.f,0.f,0.f};
                f32x4 Dc = (f32x4){0.f,0.f,0.f,0.f};
                Dh = MFMA16(ahi[mt][0], bh0, Dh);
                Dh = MFMA16(ahi[mt][1], bh1, Dh);
                Dc = MFMA16(alo[mt][0], bh0, Dc);
                Dc = MFMA16(ahi[mt][0], bl0, Dc);
                Dc = MFMA16(alo[mt][1], bh1, Dc);
                Dc = MFMA16(ahi[mt][1], bl1, Dc);
                f32x4 D = Dh + Dc * 0.00048828125f;   // 2^-11
                int elb = (tid & 192) + (mt << 4) + ((l >> 4) << 2);
                if (t < 16) {
                    f32x4 sv = *reinterpret_cast<const f32x4*>(&sT[t*260 + elb]);
                    out0[mt] += sv * D;
                } else {
                    const float* sp = &sT[(((t-16)<<2) + (cc>>2))*260 + elb];
                    #pragma unroll
                    for (int r = 0; r < 4; ++r) ob[mt][r] += sp[r] * D[r];
                }
            }
        }
    }

    // epilogue
    #pragma unroll
    for (int mt = 0; mt < 4; ++mt) {
        int elb = (tid & 192) + (mt << 4) + ((l >> 4) << 2);
        #pragma unroll
        for (int r = 0; r < 4; ++r) {
            int el = elb + r;
            int sidx = sSrc[el];
            atomicAdd(accum + (size_t)sidx*28 + cc, out0[mt][r] * 0.25f);
            float x = ob[mt][r];
            x += __shfl_xor(x, 4); x += __shfl_xor(x, 8);
            int q = cc / 3; int i = cc - q*3;
            float xq = __shfl(x, (l & 48) | q);
            if (cc < 12)
                atomicAdd(accum + (size_t)sidx*28 + 16 + cc, 0.25f * xq * sSh[el*3 + i]);
        }
    }
}

// ---------------- Layer 2 (26 tiles: 16 wa + 4 wb + 4 wc + wd + we) ----------------
__global__ __launch_bounds__(256)
void k_edge_l2(const int* __restrict__ ei, const float* __restrict__ pos,
               const float* __restrict__ edge_bond,
               const float* __restrict__ em_w1, const float* __restrict__ em_b1,
               const float* __restrict__ em_w2, const float* __restrict__ em_b2,
               const float* __restrict__ w1, const float* __restrict__ b1,
               const ushort_t* __restrict__ packW,
               const float* __restrict__ node1,
               float* __restrict__ accum2)
{
    __shared__ __align__(16) ushort_t sB[6*2048];   // 24576 B
    __shared__ __align__(16) float    sT[16*260];   // 16640 B
    __shared__ __align__(16) float    sVd[4*260];   // 4160 B (vdot*INV_SQ3 [u][e])
    __shared__ float sSh[256*3];                    // 3072 B
    __shared__ int   sSrc[256];                     // 1024 B
    __shared__ int   sDst[256];                     // 1024 B

    int tid = threadIdx.x;
    int l = tid & 63;
    int cc = l & 15;
    int e = blockIdx.x*256 + tid;
    int s = ei[e], d = ei[NE + e];

    float h[48], sh1[3], sd[16];
    compute_h<28>(e, s, d, pos, edge_bond, em_w1, em_b1, em_w2, em_b2, w1, b1,
                  node1, h, sh1, sd);
    sSrc[tid] = s;
    sDst[tid] = d;
    #pragma unroll
    for (int u = 0; u < 16; ++u) sT[u*260 + tid] = sd[u];
    #pragma unroll
    for (int k = 0; k < 3; ++k) sSh[tid*3 + k] = sh1[k];
    {
        const float4* rv = reinterpret_cast<const float4*>(node1 + (size_t)d*28 + 16);
        float4 a = rv[0], b = rv[1], c = rv[2];
        float vv[12] = {a.x,a.y,a.z,a.w, b.x,b.y,b.z,b.w, c.x,c.y,c.z,c.w};
        const float INV_SQ3 = 0.5773502691896258f;
        #pragma unroll
        for (int u = 0; u < 4; ++u)
            sVd[u*260 + tid] = (vv[u*3]*sh1[0] + vv[u*3+1]*sh1[1] + vv[u*3+2]*sh1[2]) * INV_SQ3;
    }

    uint_t hph[25], hpl[25];
    #pragma unroll
    for (int jj = 0; jj < 24; ++jj) {
        ushort_t ah, al, bh, bl;
        splitf(h[2*jj],   ah, al);
        splitf(h[2*jj+1], bh, bl);
        hph[jj] = (uint_t)ah | ((uint_t)bh << 16);
        hpl[jj] = (uint_t)al | ((uint_t)bl << 16);
    }
    hph[24] = 0x3C00u;
    hpl[24] = 0u;

    f16x8 ahi[4][2], alo[4][2];
    stage_A(sB + (tid >> 6)*2048, l, hph, hpl, ahi, alo);

    const float A0 = 0.22360679774997896f;   // 1/sqrt(20)
    const float AE = 0.3535533905932738f;    // 0.5/sqrt(2)

    f32x4 out0[4];
    float outc[4][4];
    #pragma unroll
    for (int mt = 0; mt < 4; ++mt) {
        out0[mt] = (f32x4){0.f,0.f,0.f,0.f};
        #pragma unroll
        for (int r = 0; r < 4; ++r) outc[mt][r] = 0.f;
    }

    for (int c0 = 0; c0 < 26; c0 += 6) {
        int ntl = (26 - c0 < 6) ? (26 - c0) : 6;
        __syncthreads();
        copy_chunk(sB, packW, c0, ntl, tid);
        __syncthreads();
        for (int tl = 0; tl < ntl; ++tl) {
            int t = c0 + tl;
            int bb = tl*2048 + l*8;
            f16x8 bh0 = *reinterpret_cast<const f16x8*>(&sB[bb]);
            f16x8 bl0 = *reinterpret_cast<const f16x8*>(&sB[bb + 512]);
            f16x8 bh1 = *reinterpret_cast<const f16x8*>(&sB[bb + 1024]);
            f16x8 bl1 = *reinterpret_cast<const f16x8*>(&sB[bb + 1536]);
            #pragma unroll
            for (int mt = 0; mt < 4; ++mt) {
                f32x4 Dh = (f32x4){0.f,0.f,0.f,0.f};
                f32x4 Dc = (f32x4){0.f,0.f,0.f,0.f};
                Dh = MFMA16(ahi[mt][0], bh0, Dh);
                Dh = MFMA16(ahi[mt][1], bh1, Dh);
                Dc = MFMA16(alo[mt][0], bh0, Dc);
                Dc = MFMA16(ahi[mt][0], bl0, Dc);
                Dc = MFMA16(alo[mt][1], bh1, Dc);
                Dc = MFMA16(ahi[mt][1], bl1, Dc);
                f32x4 D = Dh + Dc * 0.00048828125f;
                int elb = (tid & 192) + (mt << 4) + ((l >> 4) << 2);
                if (t < 16) {                     // wa: contract s
                    f32x4 sv = *reinterpret_cast<const f32x4*>(&sT[t*260 + elb]);
                    out0[mt] += sv * D;
                } else if (t < 20) {              // wb: contract vdot/sqrt3
                    f32x4 vd = *reinterpret_cast<const f32x4*>(&sVd[(t-16)*260 + elb]);
                    out0[mt] += vd * D;
                } else if (t < 24) {              // wc: contract s -> outc[q]
                    const float* sp = &sT[(((t-20)<<2) + (cc>>2))*260 + elb];
                    #pragma unroll
                    for (int r = 0; r < 4; ++r) outc[mt][r] += sp[r] * D[r];
                } else if (t == 24) {             // wd: + combined scatter of cols 16..27
                    #pragma unroll
                    for (int r = 0; r < 4; ++r) {
                        int el = elb + r;
                        int dv = sDst[el];
                        const float* vp = node1 + (size_t)dv*28 + 16 + (cc>>2)*3;
                        float a0 = D[r]*vp[0], a1 = D[r]*vp[1], a2 = D[r]*vp[2];
                        a0 += __shfl_xor(a0,4); a0 += __shfl_xor(a0,8);
                        a1 += __shfl_xor(a1,4); a1 += __shfl_xor(a1,8);
                        a2 += __shfl_xor(a2,4); a2 += __shfl_xor(a2,8);
                        float xc = outc[mt][r];
                        xc += __shfl_xor(xc,4); xc += __shfl_xor(xc,8);
                        int q = cc / 3; int i = cc - q*3;
                        int srcl = (l & 48) | q;
                        float g0 = __shfl(a0, srcl), g1 = __shfl(a1, srcl), g2 = __shfl(a2, srcl);
                        float oo = (i==0) ? g0 : ((i==1) ? g1 : g2);
                        float xq = __shfl(xc, srcl);
                        if (cc < 12) {
                            float sh1i = sSh[el*3 + i];
                            atomicAdd(accum2 + (size_t)sSrc[el]*40 + 16 + cc,
                                      A0 * (xq * sh1i + oo));
                        }
                    }
                } else {                          // we: cross(v, sh1), cols 28..39
                    #pragma unroll
                    for (int r = 0; r < 4; ++r) {
                        int el = elb + r;
                        int dv = sDst[el];
                        const float* vp = node1 + (size_t)dv*28 + 16 + (cc>>2)*3;
                        float vx = vp[0], vy = vp[1], vz = vp[2];
                        float sx = sSh[el*3+0], sy = sSh[el*3+1], sz = sSh[el*3+2];
                        float cx = vy*sz - vz*sy;
                        float cy = vz*sx - vx*sz;
                        float cz = vx*sy - vy*sx;
                        float a0 = D[r]*cx, a1 = D[r]*cy, a2 = D[r]*cz;
                        a0 += __shfl_xor(a0,4); a0 += __shfl_xor(a0,8);
                        a1 += __shfl_xor(a1,4); a1 += __shfl_xor(a1,8);
                        a2 += __shfl_xor(a2,4); a2 += __shfl_xor(a2,8);
                        int q = cc / 3; int i = cc - q*3;
                        int srcl = (l & 48) | q;
                        float g0 = __shfl(a0, srcl), g1 = __shfl(a1, srcl), g2 = __shfl(a2, srcl);
                        float oo = (i==0) ? g0 : ((i==1) ? g1 : g2);
                        if (cc < 12)
                            atomicAdd(accum2 + (size_t)sSrc[el]*40 + 28 + cc, AE * oo);
                    }
                }
            }
        }
    }

    // out0 scatter (cols 0..15)
    #pragma unroll
    for (int mt = 0; mt < 4; ++mt) {
        int elb = (tid & 192) + (mt << 4) + ((l >> 4) << 2);
        #pragma unroll
        for (int r = 0; r < 4; ++r) {
            int el = elb + r;
            atomicAdd(accum2 + (size_t)sSrc[el]*40 + cc, out0[mt][r] * A0);
        }
    }
}

__global__ __launch_bounds__(256)
void k_div(const float* in, float* out, const float* __restrict__ cnt, int cols, int total)
{
    int i = blockIdx.x * 256 + threadIdx.x;
    if (i >= total) return;
    int n = i / cols;
    out[i] = in[i] / fmaxf(cnt[n], 1.0f);
}

extern "C" void kernel_launch(void* const* d_in, const int* in_sizes, int n_in,
                              void* d_out, int out_size, void* d_ws, size_t ws_size,
                              hipStream_t stream) {
    const int*   x_cat     = (const int*)  d_in[0];
    const float* x_scalar  = (const float*)d_in[1];
    const float* pos       = (const float*)d_in[2];
    const int*   ei        = (const int*)  d_in[3];
    const float* edge_bond = (const float*)d_in[4];
    const float* emb       = (const float*)d_in[5];
    const float* node_w    = (const float*)d_in[6];
    const float* node_b    = (const float*)d_in[7];
    const float* em_w1     = (const float*)d_in[8];
    const float* em_b1     = (const float*)d_in[9];
    const float* em_w2     = (const float*)d_in[10];
    const float* em_b2     = (const float*)d_in[11];
    const float* c1_w1     = (const float*)d_in[12];
    const float* c1_b1     = (const float*)d_in[13];
    const float* c1_w2     = (const float*)d_in[14];
    const float* c1_b2     = (const float*)d_in[15];
    const float* c2_w1     = (const float*)d_in[16];
    const float* c2_b1     = (const float*)d_in[17];
    const float* c2_w2     = (const float*)d_in[18];
    const float* c2_b2     = (const float*)d_in[19];

    float* ws     = (float*)d_ws;
    float* node0  = ws;                  // NN*16 = 320000
    float* accum1 = ws + 320000;         // NN*28 = 560000 (becomes node1 in place)
    float* accum2 = ws + 880000;         // NN*40 = 800000
    float* cnt    = ws + 1680000;        // NN    = 20000
    ushort_t* packA = (ushort_t*)(ws + 1700000);            // 20*2048 ushorts
    ushort_t* packB = packA + 20*2048;                      // 26*2048 ushorts

    hipMemsetAsync(accum1, 0, (size_t)(560000 + 800000 + 20000) * sizeof(float), stream);

    k_pack<<<(20*128 + 255) / 256, 256, 0, stream>>>(c1_w2, c1_b2, packA, 320, 20);
    k_pack<<<(26*128 + 255) / 256, 256, 0, stream>>>(c2_w2, c2_b2, packB, 416, 26);

    k_node_feat<<<(NN + 255) / 256, 256, 0, stream>>>(
        x_cat, x_scalar, emb, node_w, node_b, node0);

    k_edge_l1<<<NE / 256, 256, 0, stream>>>(
        ei, pos, edge_bond, em_w1, em_b1, em_w2, em_b2,
        c1_w1, c1_b1, packA, node0, accum1, cnt);

    k_div<<<(560000 + 255) / 256, 256, 0, stream>>>(accum1, accum1, cnt, 28, 560000);

    k_edge_l2<<<NE / 256, 256, 0, stream>>>(
        ei, pos, edge_bond, em_w1, em_b1, em_w2, em_b2,
        c2_w1, c2_b1, packB, accum1, accum2);

    k_div<<<(800000 + 255) / 256, 256, 0, stream>>>(accum2, (float*)d_out, cnt, 40, 800000);
}

// Round 7
// 328.576 us; speedup vs baseline: 13.7375x; 1.0367x over previous
//
#include <hip/hip_runtime.h>
#include <math.h>

#define NN 20000
#define NE 320000

typedef _Float16 f16x8 __attribute__((ext_vector_type(8)));
typedef float f32x4 __attribute__((ext_vector_type(4)));
typedef unsigned short ushort_t;
typedef unsigned int uint_t;

#define MFMA16(A,B,C) __builtin_amdgcn_mfma_f32_16x16x32_f16((A),(B),(C),0,0,0)
#define LDS_FENCE() do{ asm volatile("s_waitcnt lgkmcnt(0)" ::: "memory"); __builtin_amdgcn_sched_barrier(0);}while(0)

static_assert(NE % 256 == 0, "edge grid must tile exactly");

__device__ __forceinline__ float frelu(float x){ return fmaxf(x, 0.0f); }

// split x = hi + lo * 2^-11  (lo stored pre-scaled by 2^11 to stay f16-normal)
__device__ __forceinline__ void splitf(float x, ushort_t& h, ushort_t& l){
    _Float16 hh = (_Float16)x;
    float r = (x - (float)hh) * 2048.0f;
    _Float16 ll = (_Float16)r;
    union { _Float16 f; ushort_t u; } ch, cl;
    ch.f = hh; cl.f = ll;
    h = ch.u; l = cl.u;
}

__device__ __forceinline__ void edge_embed(
    int e, int s, int d,
    const float* __restrict__ pos,
    const float* __restrict__ edge_bond,
    const float* __restrict__ em_w1, const float* __restrict__ em_b1,
    const float* __restrict__ em_w2, const float* __restrict__ em_b2,
    float* eemb, float* sh1)
{
    float vx = pos[d*3+0] - pos[s*3+0];
    float vy = pos[d*3+1] - pos[s*3+1];
    float vz = pos[d*3+2] - pos[s*3+2];
    float d2 = vx*vx + vy*vy + vz*vz + 1e-12f;
    float dist = sqrtf(d2);
    float inv = 1.0f / (dist + 1e-8f);
    const float SQ3 = 1.7320508075688772f;
    sh1[0] = SQ3 * vx * inv;
    sh1[1] = SQ3 * vy * inv;
    sh1[2] = SQ3 * vz * inv;

    float ein[42];
    #pragma unroll
    for (int t = 0; t < 10; ++t) ein[t] = edge_bond[e*10 + t];
    const float coeff = -19.22f;            // -0.5 / (5/31)^2
    const float step  = 5.0f / 31.0f;
    #pragma unroll
    for (int k = 0; k < 32; ++k) {
        float dd = dist - step * (float)k;
        ein[10+k] = __expf(coeff * dd * dd);
    }

    float t1[16];
    #pragma unroll
    for (int j = 0; j < 16; ++j) t1[j] = em_b1[j];
    #pragma unroll
    for (int t = 0; t < 42; ++t) {
        float v = ein[t];
        #pragma unroll
        for (int j = 0; j < 16; ++j) t1[j] += v * em_w1[t*16 + j];
    }
    #pragma unroll
    for (int j = 0; j < 16; ++j) t1[j] = frelu(t1[j]);

    #pragma unroll
    for (int j = 0; j < 16; ++j) eemb[j] = em_b2[j];
    #pragma unroll
    for (int t = 0; t < 16; ++t) {
        float v = t1[t];
        #pragma unroll
        for (int j = 0; j < 16; ++j) eemb[j] += v * em_w2[t*16 + j];
    }
}

template<int STRIDE>
__device__ __forceinline__ void compute_h(
    int e, int s, int d,
    const float* __restrict__ pos, const float* __restrict__ edge_bond,
    const float* __restrict__ em_w1, const float* __restrict__ em_b1,
    const float* __restrict__ em_w2, const float* __restrict__ em_b2,
    const float* __restrict__ w1, const float* __restrict__ b1,
    const float* __restrict__ node, float* h, float* sh1, float* sdout)
{
    float ea[48];
    edge_embed(e, s, d, pos, edge_bond, em_w1, em_b1, em_w2, em_b2, ea, sh1);
    const float4* rs = reinterpret_cast<const float4*>(node + (size_t)s*STRIDE);
    const float4* rd = reinterpret_cast<const float4*>(node + (size_t)d*STRIDE);
    #pragma unroll
    for (int k = 0; k < 4; ++k) {
        float4 q = rs[k];
        ea[16+4*k] = q.x; ea[17+4*k] = q.y; ea[18+4*k] = q.z; ea[19+4*k] = q.w;
        float4 r = rd[k];
        ea[32+4*k] = r.x; ea[33+4*k] = r.y; ea[34+4*k] = r.z; ea[35+4*k] = r.w;
    }
    #pragma unroll
    for (int k = 0; k < 16; ++k) sdout[k] = ea[32+k];
    #pragma unroll
    for (int j = 0; j < 48; ++j) h[j] = b1[j];
    #pragma unroll
    for (int t = 0; t < 48; ++t) {
        float v = ea[t];
        #pragma unroll
        for (int j = 0; j < 48; ++j) h[j] += v * w1[t*48 + j];
    }
    #pragma unroll
    for (int j = 0; j < 48; ++j) h[j] = frelu(h[j]);
}

// One-time pack of W2' (K=49 rows incl bias, zero-pad to 64) into global hi/lo
// fragment layout: tile*2048 + kb*1024 + ll*8 (+512 for lo), ushort units.
__global__ __launch_bounds__(256)
void k_pack(const float* __restrict__ w2, const float* __restrict__ b2,
            ushort_t* __restrict__ out, int NC, int ntiles)
{
    int slot = blockIdx.x*256 + threadIdx.x;
    if (slot >= ntiles*128) return;
    int tl = slot >> 7; int r7 = slot & 127; int kb = r7 >> 6; int ll = r7 & 63;
    int col = tl*16 + (ll & 15);
    int k0 = (kb<<5) + ((ll>>4)<<3);
    uint_t hw[4], lw[4];
    #pragma unroll
    for (int p = 0; p < 4; ++p) {
        int ka = k0 + 2*p, kb2 = k0 + 2*p + 1;
        float va = (ka < 48) ? w2[ka*NC + col] : (ka == 48 ? b2[col] : 0.0f);
        float vb = (kb2 < 48) ? w2[kb2*NC + col] : (kb2 == 48 ? b2[col] : 0.0f);
        ushort_t ah, al, bh, bl;
        splitf(va, ah, al);
        splitf(vb, bh, bl);
        hw[p] = (uint_t)ah | ((uint_t)bh << 16);
        lw[p] = (uint_t)al | ((uint_t)bl << 16);
    }
    int base = tl*2048 + kb*1024 + ll*8;
    *reinterpret_cast<uint4*>(&out[base])       = make_uint4(hw[0], hw[1], hw[2], hw[3]);
    *reinterpret_cast<uint4*>(&out[base + 512]) = make_uint4(lw[0], lw[1], lw[2], lw[3]);
}

// B fragments for one tile, read straight from L2 (coalesced: lane l -> l*16B).
struct B4 { f16x8 h0, l0, h1, l1; };
__device__ __forceinline__ B4 loadB(const f16x8* __restrict__ g, int t, int l) {
    B4 b;
    const f16x8* p = g + t*256 + l;
    b.h0 = p[0];
    b.l0 = p[64];
    b.h1 = p[128];
    b.l1 = p[192];
    return b;
}

// Per-wave A-frag staging through a 4 KB bounce (hi+lo in one pass, 2 fences/mt).
__device__ __forceinline__ void stage_A(ushort_t* bounce, int l,
                                        const uint_t* hph, const uint_t* hpl,
                                        f16x8 ahi[4][2], f16x8 alo[4][2])
{
    #pragma unroll
    for (int t = 0; t < 4; ++t)
        *reinterpret_cast<uint4*>(&bounce[l*32 + t*8]) = make_uint4(0,0,0,0);
    LDS_FENCE();
    #pragma unroll
    for (int mt = 0; mt < 4; ++mt) {
        if ((l >> 4) == mt) {
            #pragma unroll
            for (int jj = 0; jj < 25; ++jj) {
                int k = jj*2, kb = k >> 5, kk = k & 31;
                int lr = (l & 15) + ((kk >> 3) << 4);
                int off = kb*512 + lr*8 + (kk & 7);
                *reinterpret_cast<uint_t*>(&bounce[off])        = hph[jj];
                *reinterpret_cast<uint_t*>(&bounce[1024 + off]) = hpl[jj];
            }
        }
        LDS_FENCE();
        ahi[mt][0] = *reinterpret_cast<const f16x8*>(&bounce[l*8]);
        ahi[mt][1] = *reinterpret_cast<const f16x8*>(&bounce[512 + l*8]);
        alo[mt][0] = *reinterpret_cast<const f16x8*>(&bounce[1024 + l*8]);
        alo[mt][1] = *reinterpret_cast<const f16x8*>(&bounce[1536 + l*8]);
        LDS_FENCE();
    }
}

__global__ __launch_bounds__(256)
void k_node_feat(const int* __restrict__ x_cat, const float* __restrict__ x_scalar,
                 const float* __restrict__ emb, const float* __restrict__ node_w,
                 const float* __restrict__ node_b, float* __restrict__ node0)
{
    int n = blockIdx.x * 256 + threadIdx.x;
    if (n >= NN) return;
    float acc[16];
    #pragma unroll
    for (int k = 0; k < 16; ++k) acc[k] = node_b[k];
    #pragma unroll
    for (int c = 0; c < 10; ++c) {
        int idx = x_cat[n*10 + c];
        const float4* row = reinterpret_cast<const float4*>(emb + (c*119 + idx)*16);
        #pragma unroll
        for (int k = 0; k < 4; ++k) {
            float4 q = row[k];
            acc[4*k+0] += q.x; acc[4*k+1] += q.y; acc[4*k+2] += q.z; acc[4*k+3] += q.w;
        }
    }
    #pragma unroll
    for (int t = 0; t < 32; ++t) {
        float xs = x_scalar[n*32 + t];
        #pragma unroll
        for (int k = 0; k < 16; ++k) acc[k] += xs * node_w[t*16 + k];
    }
    #pragma unroll
    for (int k = 0; k < 16; ++k) node0[n*16 + k] = acc[k];
}

// ---------------- Layer 1 (20 tiles: 16 wa + 4 wb) ----------------
__global__ __launch_bounds__(256)
void k_edge_l1(const int* __restrict__ ei, const float* __restrict__ pos,
               const float* __restrict__ edge_bond,
               const float* __restrict__ em_w1, const float* __restrict__ em_b1,
               const float* __restrict__ em_w2, const float* __restrict__ em_b2,
               const float* __restrict__ w1, const float* __restrict__ b1,
               const ushort_t* __restrict__ packW,
               const float* __restrict__ node0,
               float* __restrict__ accum, float* __restrict__ cnt)
{
    // union: [0,16384) stage_A bounce (dead after staging) / sT+sSh+sSrc live after
    __shared__ __align__(16) unsigned char smem[20736];
    float* sT  = (float*)smem;                    // 16*260*4 = 16640
    float* sSh = (float*)(smem + 16640);          // 3072
    int*   sSrc= (int*)(smem + 19712);            // 1024

    int tid = threadIdx.x;
    int l = tid & 63;
    int cc = l & 15;
    int e = blockIdx.x*256 + tid;
    int s = ei[e], d = ei[NE + e];

    float h[48], sh1[3], sd[16];
    compute_h<16>(e, s, d, pos, edge_bond, em_w1, em_b1, em_w2, em_b2, w1, b1,
                  node0, h, sh1, sd);
    atomicAdd(cnt + s, 1.0f);

    uint_t hph[25], hpl[25];
    #pragma unroll
    for (int jj = 0; jj < 24; ++jj) {
        ushort_t ah, al, bh, bl;
        splitf(h[2*jj],   ah, al);
        splitf(h[2*jj+1], bh, bl);
        hph[jj] = (uint_t)ah | ((uint_t)bh << 16);
        hpl[jj] = (uint_t)al | ((uint_t)bl << 16);
    }
    hph[24] = 0x3C00u;  // k=48 -> 1.0 (bias feature), k=49 -> 0
    hpl[24] = 0u;

    f16x8 ahi[4][2], alo[4][2];
    stage_A((ushort_t*)smem + (tid >> 6)*2048, l, hph, hpl, ahi, alo);

    __syncthreads();            // bounce dead; now fill the union region
    sSrc[tid] = s;
    #pragma unroll
    for (int u = 0; u < 16; ++u) sT[u*260 + tid] = sd[u];
    #pragma unroll
    for (int k = 0; k < 3; ++k) sSh[tid*3 + k] = sh1[k];
    __syncthreads();

    f32x4 out0[4];
    float ob[4][4];
    #pragma unroll
    for (int mt = 0; mt < 4; ++mt) {
        out0[mt] = (f32x4){0.f,0.f,0.f,0.f};
        #pragma unroll
        for (int r = 0; r < 4; ++r) ob[mt][r] = 0.f;
    }

    const f16x8* gB = reinterpret_cast<const f16x8*>(packW);
    B4 cur = loadB(gB, 0, l);
    #pragma unroll 1
    for (int t = 0; t < 20; ++t) {
        B4 nxt;
        if (t + 1 < 20) nxt = loadB(gB, t + 1, l);
        #pragma unroll
        for (int mt = 0; mt < 4; ++mt) {
            f32x4 Dh = (f32x4){0.f,0.f,0.f,0.f};
            f32x4 Dc = (f32x4){0.f,0.f,0.f,0.f};
            Dh = MFMA16(ahi[mt][0], cur.h0, Dh);
            Dh = MFMA16(ahi[mt][1], cur.h1, Dh);
            Dc = MFMA16(alo[mt][0], cur.h0, Dc);
            Dc = MFMA16(ahi[mt][0], cur.l0, Dc);
            Dc = MFMA16(alo[mt][1], cur.h1, Dc);
            Dc = MFMA16(ahi[mt][1], cur.l1, Dc);
            f32x4 D = Dh + Dc * 0.00048828125f;   // 2^-11
            int elb = (tid & 192) + (mt << 4) + ((l >> 4) << 2);
            if (t < 16) {
                f32x4 sv = *reinterpret_cast<const f32x4*>(&sT[t*260 + elb]);
                out0[mt] += sv * D;
            } else {
                const float* sp = &sT[(((t-16)<<2) + (cc>>2))*260 + elb];
                #pragma unroll
                for (int r = 0; r < 4; ++r) ob[mt][r] += sp[r] * D[r];
            }
        }
        cur = nxt;
    }

    // epilogue
    #pragma unroll
    for (int mt = 0; mt < 4; ++mt) {
        int elb = (tid & 192) + (mt << 4) + ((l >> 4) << 2);
        #pragma unroll
        for (int r = 0; r < 4; ++r) {
            int el = elb + r;
            int sidx = sSrc[el];
            atomicAdd(accum + (size_t)sidx*28 + cc, out0[mt][r] * 0.25f);
            float x = ob[mt][r];
            x += __shfl_xor(x, 4); x += __shfl_xor(x, 8);
            int q = cc / 3; int i = cc - q*3;
            float xq = __shfl(x, (l & 48) | q);
            if (cc < 12)
                atomicAdd(accum + (size_t)sidx*28 + 16 + cc, 0.25f * xq * sSh[el*3 + i]);
        }
    }
}

// ---------------- Layer 2 (26 tiles: 16 wa + 4 wb + 4 wc + wd + we) ----------------
__global__ __launch_bounds__(256)
void k_edge_l2(const int* __restrict__ ei, const float* __restrict__ pos,
               const float* __restrict__ edge_bond,
               const float* __restrict__ em_w1, const float* __restrict__ em_b1,
               const float* __restrict__ em_w2, const float* __restrict__ em_b2,
               const float* __restrict__ w1, const float* __restrict__ b1,
               const ushort_t* __restrict__ packW,
               const float* __restrict__ node1,
               float* __restrict__ accum2)
{
    __shared__ __align__(16) unsigned char smem[25920];
    float* sT  = (float*)smem;                    // 16640
    float* sVd = (float*)(smem + 16640);          // 4160
    float* sSh = (float*)(smem + 20800);          // 3072
    int*   sSrc= (int*)(smem + 23872);            // 1024
    int*   sDst= (int*)(smem + 24896);            // 1024

    int tid = threadIdx.x;
    int l = tid & 63;
    int cc = l & 15;
    int e = blockIdx.x*256 + tid;
    int s = ei[e], d = ei[NE + e];

    float h[48], sh1[3], sd[16];
    compute_h<28>(e, s, d, pos, edge_bond, em_w1, em_b1, em_w2, em_b2, w1, b1,
                  node1, h, sh1, sd);

    float vdr[4];
    {
        const float4* rv = reinterpret_cast<const float4*>(node1 + (size_t)d*28 + 16);
        float4 a = rv[0], b = rv[1], c = rv[2];
        float vv[12] = {a.x,a.y,a.z,a.w, b.x,b.y,b.z,b.w, c.x,c.y,c.z,c.w};
        const float INV_SQ3 = 0.5773502691896258f;
        #pragma unroll
        for (int u = 0; u < 4; ++u)
            vdr[u] = (vv[u*3]*sh1[0] + vv[u*3+1]*sh1[1] + vv[u*3+2]*sh1[2]) * INV_SQ3;
    }

    uint_t hph[25], hpl[25];
    #pragma unroll
    for (int jj = 0; jj < 24; ++jj) {
        ushort_t ah, al, bh, bl;
        splitf(h[2*jj],   ah, al);
        splitf(h[2*jj+1], bh, bl);
        hph[jj] = (uint_t)ah | ((uint_t)bh << 16);
        hpl[jj] = (uint_t)al | ((uint_t)bl << 16);
    }
    hph[24] = 0x3C00u;
    hpl[24] = 0u;

    f16x8 ahi[4][2], alo[4][2];
    stage_A((ushort_t*)smem + (tid >> 6)*2048, l, hph, hpl, ahi, alo);

    __syncthreads();
    sSrc[tid] = s;
    sDst[tid] = d;
    #pragma unroll
    for (int u = 0; u < 16; ++u) sT[u*260 + tid] = sd[u];
    #pragma unroll
    for (int u = 0; u < 4; ++u) sVd[u*260 + tid] = vdr[u];
    #pragma unroll
    for (int k = 0; k < 3; ++k) sSh[tid*3 + k] = sh1[k];
    __syncthreads();

    const float A0 = 0.22360679774997896f;   // 1/sqrt(20)
    const float AE = 0.3535533905932738f;    // 0.5/sqrt(2)

    f32x4 out0[4];
    float outc[4][4];
    #pragma unroll
    for (int mt = 0; mt < 4; ++mt) {
        out0[mt] = (f32x4){0.f,0.f,0.f,0.f};
        #pragma unroll
        for (int r = 0; r < 4; ++r) outc[mt][r] = 0.f;
    }

    const f16x8* gB = reinterpret_cast<const f16x8*>(packW);
    B4 cur = loadB(gB, 0, l);
    #pragma unroll 1
    for (int t = 0; t < 26; ++t) {
        B4 nxt;
        if (t + 1 < 26) nxt = loadB(gB, t + 1, l);
        #pragma unroll
        for (int mt = 0; mt < 4; ++mt) {
            f32x4 Dh = (f32x4){0.f,0.f,0.f,0.f};
            f32x4 Dc = (f32x4){0.f,0.f,0.f,0.f};
            Dh = MFMA16(ahi[mt][0], cur.h0, Dh);
            Dh = MFMA16(ahi[mt][1], cur.h1, Dh);
            Dc = MFMA16(alo[mt][0], cur.h0, Dc);
            Dc = MFMA16(ahi[mt][0], cur.l0, Dc);
            Dc = MFMA16(alo[mt][1], cur.h1, Dc);
            Dc = MFMA16(ahi[mt][1], cur.l1, Dc);
            f32x4 D = Dh + Dc * 0.00048828125f;
            int elb = (tid & 192) + (mt << 4) + ((l >> 4) << 2);
            if (t < 16) {                     // wa: contract s
                f32x4 sv = *reinterpret_cast<const f32x4*>(&sT[t*260 + elb]);
                out0[mt] += sv * D;
            } else if (t < 20) {              // wb: contract vdot/sqrt3
                f32x4 vd = *reinterpret_cast<const f32x4*>(&sVd[(t-16)*260 + elb]);
                out0[mt] += vd * D;
            } else if (t < 24) {              // wc: contract s -> outc[q]
                const float* sp = &sT[(((t-20)<<2) + (cc>>2))*260 + elb];
                #pragma unroll
                for (int r = 0; r < 4; ++r) outc[mt][r] += sp[r] * D[r];
            } else if (t == 24) {             // wd: + combined scatter of cols 16..27
                #pragma unroll
                for (int r = 0; r < 4; ++r) {
                    int el = elb + r;
                    int dv = sDst[el];
                    const float* vp = node1 + (size_t)dv*28 + 16 + (cc>>2)*3;
                    float a0 = D[r]*vp[0], a1 = D[r]*vp[1], a2 = D[r]*vp[2];
                    a0 += __shfl_xor(a0,4); a0 += __shfl_xor(a0,8);
                    a1 += __shfl_xor(a1,4); a1 += __shfl_xor(a1,8);
                    a2 += __shfl_xor(a2,4); a2 += __shfl_xor(a2,8);
                    float xc = outc[mt][r];
                    xc += __shfl_xor(xc,4); xc += __shfl_xor(xc,8);
                    int q = cc / 3; int i = cc - q*3;
                    int srcl = (l & 48) | q;
                    float g0 = __shfl(a0, srcl), g1 = __shfl(a1, srcl), g2 = __shfl(a2, srcl);
                    float oo = (i==0) ? g0 : ((i==1) ? g1 : g2);
                    float xq = __shfl(xc, srcl);
                    if (cc < 12) {
                        float sh1i = sSh[el*3 + i];
                        atomicAdd(accum2 + (size_t)sSrc[el]*40 + 16 + cc,
                                  A0 * (xq * sh1i + oo));
                    }
                }
            } else {                          // we: cross(v, sh1), cols 28..39
                #pragma unroll
                for (int r = 0; r < 4; ++r) {
                    int el = elb + r;
                    int dv = sDst[el];
                    const float* vp = node1 + (size_t)dv*28 + 16 + (cc>>2)*3;
                    float vx = vp[0], vy = vp[1], vz = vp[2];
                    float sx = sSh[el*3+0], sy = sSh[el*3+1], sz = sSh[el*3+2];
                    float cx = vy*sz - vz*sy;
                    float cy = vz*sx - vx*sz;
                    float cz = vx*sy - vy*sx;
                    float a0 = D[r]*cx, a1 = D[r]*cy, a2 = D[r]*cz;
                    a0 += __shfl_xor(a0,4); a0 += __shfl_xor(a0,8);
                    a1 += __shfl_xor(a1,4); a1 += __shfl_xor(a1,8);
                    a2 += __shfl_xor(a2,4); a2 += __shfl_xor(a2,8);
                    int q = cc / 3; int i = cc - q*3;
                    int srcl = (l & 48) | q;
                    float g0 = __shfl(a0, srcl), g1 = __shfl(a1, srcl), g2 = __shfl(a2, srcl);
                    float oo = (i==0) ? g0 : ((i==1) ? g1 : g2);
                    if (cc < 12)
                        atomicAdd(accum2 + (size_t)sSrc[el]*40 + 28 + cc, AE * oo);
                }
            }
        }
        cur = nxt;
    }

    // out0 scatter (cols 0..15)
    #pragma unroll
    for (int mt = 0; mt < 4; ++mt) {
        int elb = (tid & 192) + (mt << 4) + ((l >> 4) << 2);
        #pragma unroll
        for (int r = 0; r < 4; ++r) {
            int el = elb + r;
            atomicAdd(accum2 + (size_t)sSrc[el]*40 + cc, out0[mt][r] * A0);
        }
    }
}

__global__ __launch_bounds__(256)
void k_div(const float* in, float* out, const float* __restrict__ cnt, int cols, int total)
{
    int i = blockIdx.x * 256 + threadIdx.x;
    if (i >= total) return;
    int n = i / cols;
    out[i] = in[i] / fmaxf(cnt[n], 1.0f);
}

extern "C" void kernel_launch(void* const* d_in, const int* in_sizes, int n_in,
                              void* d_out, int out_size, void* d_ws, size_t ws_size,
                              hipStream_t stream) {
    const int*   x_cat     = (const int*)  d_in[0];
    const float* x_scalar  = (const float*)d_in[1];
    const float* pos       = (const float*)d_in[2];
    const int*   ei        = (const int*)  d_in[3];
    const float* edge_bond = (const float*)d_in[4];
    const float* emb       = (const float*)d_in[5];
    const float* node_w    = (const float*)d_in[6];
    const float* node_b    = (const float*)d_in[7];
    const float* em_w1     = (const float*)d_in[8];
    const float* em_b1     = (const float*)d_in[9];
    const float* em_w2     = (const float*)d_in[10];
    const float* em_b2     = (const float*)d_in[11];
    const float* c1_w1     = (const float*)d_in[12];
    const float* c1_b1     = (const float*)d_in[13];
    const float* c1_w2     = (const float*)d_in[14];
    const float* c1_b2     = (const float*)d_in[15];
    const float* c2_w1     = (const float*)d_in[16];
    const float* c2_b1     = (const float*)d_in[17];
    const float* c2_w2     = (const float*)d_in[18];
    const float* c2_b2     = (const float*)d_in[19];

    float* ws     = (float*)d_ws;
    float* node0  = ws;                  // NN*16 = 320000
    float* accum1 = ws + 320000;         // NN*28 = 560000 (becomes node1 in place)
    float* accum2 = ws + 880000;         // NN*40 = 800000
    float* cnt    = ws + 1680000;        // NN    = 20000
    ushort_t* packA = (ushort_t*)(ws + 1700000);            // 20*2048 ushorts
    ushort_t* packB = packA + 20*2048;                      // 26*2048 ushorts

    hipMemsetAsync(accum1, 0, (size_t)(560000 + 800000 + 20000) * sizeof(float), stream);

    k_pack<<<(20*128 + 255) / 256, 256, 0, stream>>>(c1_w2, c1_b2, packA, 320, 20);
    k_pack<<<(26*128 + 255) / 256, 256, 0, stream>>>(c2_w2, c2_b2, packB, 416, 26);

    k_node_feat<<<(NN + 255) / 256, 256, 0, stream>>>(
        x_cat, x_scalar, emb, node_w, node_b, node0);

    k_edge_l1<<<NE / 256, 256, 0, stream>>>(
        ei, pos, edge_bond, em_w1, em_b1, em_w2, em_b2,
        c1_w1, c1_b1, packA, node0, accum1, cnt);

    k_div<<<(560000 + 255) / 256, 256, 0, stream>>>(accum1, accum1, cnt, 28, 560000);

    k_edge_l2<<<NE / 256, 256, 0, stream>>>(
        ei, pos, edge_bond, em_w1, em_b1, em_w2, em_b2,
        c2_w1, c2_b1, packB, accum1, accum2);

    k_div<<<(800000 + 255) / 256, 256, 0, stream>>>(accum2, (float*)d_out, cnt, 40, 800000);
}